// Round 1
// baseline (99.704 us; speedup 1.0000x reference)
//
#include <hip/hip_runtime.h>
#include <hip/hip_bf16.h>

#define N_ATOMS 2048
#define C_DIM   128
#define C_PAIR  16
#define N_HEADS 4
#define D_HEAD  32
#define BLK_K   128
#define LN_EPS  1e-5f

// ---------------------------------------------------------------------------
// K1: LayerNorm(x) -> h (LDS), then q/k/v = h @ W{q,k,v}.T
// 256 threads, 8 rows per block, grid = 2048/8 = 256
// ---------------------------------------------------------------------------
__global__ __launch_bounds__(256) void ln_qkv_kernel(
    const float* __restrict__ x,
    const float* __restrict__ Wq, const float* __restrict__ Wk,
    const float* __restrict__ Wv,
    float* __restrict__ q, float* __restrict__ k, float* __restrict__ v)
{
    __shared__ __align__(16) float hs[8][128];
    const int t = threadIdx.x;
    const int row0 = blockIdx.x * 8;

    // --- load + LayerNorm: 32 threads per row, 4 cols each ---
    {
        const int r = t >> 5;      // 0..7
        const int l = t & 31;      // 0..31
        const float4 xv = reinterpret_cast<const float4*>(
            x + (size_t)(row0 + r) * C_DIM)[l];
        float s  = xv.x + xv.y + xv.z + xv.w;
        float ss = xv.x*xv.x + xv.y*xv.y + xv.z*xv.z + xv.w*xv.w;
        #pragma unroll
        for (int m = 16; m >= 1; m >>= 1) {
            s  += __shfl_xor(s,  m);
            ss += __shfl_xor(ss, m);
        }
        const float mu  = s * (1.0f / 128.0f);
        const float var = ss * (1.0f / 128.0f) - mu * mu;
        const float inv = rsqrtf(var + LN_EPS);
        float4 hv;
        hv.x = (xv.x - mu) * inv;
        hv.y = (xv.y - mu) * inv;
        hv.z = (xv.z - mu) * inv;
        hv.w = (xv.w - mu) * inv;
        *reinterpret_cast<float4*>(&hs[r][l * 4]) = hv;
    }
    __syncthreads();

    // --- 3 projections: thread (c, half) computes 4 rows for output col c ---
    const int c    = t & 127;
    const int half = t >> 7;   // 0 or 1
    const float* Ws[3] = {Wq, Wk, Wv};
    float*       Os[3] = {q, k, v};
    #pragma unroll
    for (int w = 0; w < 3; ++w) {
        const float4* Wr = reinterpret_cast<const float4*>(Ws[w] + (size_t)c * C_DIM);
        float acc0 = 0.f, acc1 = 0.f, acc2 = 0.f, acc3 = 0.f;
        const int rb = half * 4;
        #pragma unroll 8
        for (int jq = 0; jq < 32; ++jq) {
            const float4 w4 = Wr[jq];
            const float4 h0 = *reinterpret_cast<const float4*>(&hs[rb + 0][jq * 4]);
            const float4 h1 = *reinterpret_cast<const float4*>(&hs[rb + 1][jq * 4]);
            const float4 h2 = *reinterpret_cast<const float4*>(&hs[rb + 2][jq * 4]);
            const float4 h3 = *reinterpret_cast<const float4*>(&hs[rb + 3][jq * 4]);
            acc0 += w4.x*h0.x + w4.y*h0.y + w4.z*h0.z + w4.w*h0.w;
            acc1 += w4.x*h1.x + w4.y*h1.y + w4.z*h1.z + w4.w*h1.w;
            acc2 += w4.x*h2.x + w4.y*h2.y + w4.z*h2.z + w4.w*h2.w;
            acc3 += w4.x*h3.x + w4.y*h3.y + w4.z*h3.z + w4.w*h3.w;
        }
        float* O = Os[w];
        O[(size_t)(row0 + rb + 0) * C_DIM + c] = acc0;
        O[(size_t)(row0 + rb + 1) * C_DIM + c] = acc1;
        O[(size_t)(row0 + rb + 2) * C_DIM + c] = acc2;
        O[(size_t)(row0 + rb + 3) * C_DIM + c] = acc3;
    }
}

// ---------------------------------------------------------------------------
// K2: block-sparse attention. One block (128 threads) per query row.
// Phase A: thread b gathers k[j_b] (512B contiguous), 4 head dots + pair bias.
// Phase B: block softmax per head (head = t>>5 group of 32 threads).
// Phase C: thread t computes output dim t; v reads fully coalesced.
// ---------------------------------------------------------------------------
__global__ __launch_bounds__(128) void attn_kernel(
    const float* __restrict__ q, const float* __restrict__ k,
    const float* __restrict__ v, const float* __restrict__ pair,
    const int*  __restrict__ bidx, const float* __restrict__ Wb,
    float* __restrict__ attn_out)
{
    __shared__ __align__(16) float qS[128];
    __shared__ int   idxS[128];
    __shared__ float S[4][128];

    const int t   = threadIdx.x;
    const int row = blockIdx.x;

    qS[t] = q[(size_t)row * C_DIM + t];
    const int j = bidx[(size_t)row * BLK_K + t];
    idxS[t] = j;
    __syncthreads();

    // --- scores for 4 heads ---
    const float4* kr = reinterpret_cast<const float4*>(k + (size_t)j * C_DIM);
    const float4* q4 = reinterpret_cast<const float4*>(qS);
    float sc[4];
    #pragma unroll
    for (int h = 0; h < 4; ++h) {
        float a = 0.f;
        #pragma unroll
        for (int d = 0; d < 8; ++d) {
            const float4 kk = kr[h * 8 + d];
            const float4 qq = q4[h * 8 + d];
            a += kk.x*qq.x + kk.y*qq.y + kk.z*qq.z + kk.w*qq.w;
        }
        sc[h] = a;
    }

    // --- pair bias: gather 16 contiguous f32, mean, scale by Wb[h] ---
    const float4* pr = reinterpret_cast<const float4*>(
        pair + ((size_t)row * N_ATOMS + (size_t)j) * C_PAIR);
    const float4 p0 = pr[0], p1 = pr[1], p2 = pr[2], p3 = pr[3];
    const float pm = (p0.x+p0.y+p0.z+p0.w + p1.x+p1.y+p1.z+p1.w +
                      p2.x+p2.y+p2.z+p2.w + p3.x+p3.y+p3.z+p3.w) * (1.0f/16.0f);
    const float scale = 0.17677669529663687f;  // 1/sqrt(32)
    #pragma unroll
    for (int h = 0; h < 4; ++h)
        S[h][t] = sc[h] * scale + pm * Wb[h];
    __syncthreads();

    // --- softmax over the 128 keys, per head (32 threads per head) ---
    {
        const int g = t >> 5, l = t & 31;
        const float v0 = S[g][l], v1 = S[g][l + 32],
                    v2 = S[g][l + 64], v3 = S[g][l + 96];
        float mx = fmaxf(fmaxf(v0, v1), fmaxf(v2, v3));
        #pragma unroll
        for (int m = 16; m >= 1; m >>= 1) mx = fmaxf(mx, __shfl_xor(mx, m));
        const float e0 = __expf(v0 - mx), e1 = __expf(v1 - mx),
                    e2 = __expf(v2 - mx), e3 = __expf(v3 - mx);
        float sm = e0 + e1 + e2 + e3;
        #pragma unroll
        for (int m = 16; m >= 1; m >>= 1) sm += __shfl_xor(sm, m);
        const float rs = 1.0f / sm;
        S[g][l]      = e0 * rs;
        S[g][l + 32] = e1 * rs;
        S[g][l + 64] = e2 * rs;
        S[g][l + 96] = e3 * rs;
    }
    __syncthreads();

    // --- PV: thread t = output dim (head = t>>5); coalesced v reads ---
    const int hh = t >> 5;
    float acc = 0.f;
    #pragma unroll 8
    for (int b = 0; b < BLK_K; ++b) {
        acc += S[hh][b] * v[(size_t)idxS[b] * C_DIM + t];
    }
    attn_out[(size_t)row * C_DIM + t] = acc;
}

// ---------------------------------------------------------------------------
// K3: x1 = x + attn_out @ Wout.T ; h2 = LayerNorm(x1)
// ---------------------------------------------------------------------------
__global__ __launch_bounds__(256) void proj_ln_kernel(
    const float* __restrict__ attn_out, const float* __restrict__ x,
    const float* __restrict__ Wout,
    float* __restrict__ x1, float* __restrict__ h2)
{
    __shared__ __align__(16) float as[8][128];
    __shared__ __align__(16) float ys[8][128];
    const int t = threadIdx.x;
    const int row0 = blockIdx.x * 8;

    {
        const int r = t >> 5, l = t & 31;
        const float4 av = reinterpret_cast<const float4*>(
            attn_out + (size_t)(row0 + r) * C_DIM)[l];
        *reinterpret_cast<float4*>(&as[r][l * 4]) = av;
    }
    __syncthreads();

    const int c = t & 127, half = t >> 7;
    {
        const float4* Wr = reinterpret_cast<const float4*>(Wout + (size_t)c * C_DIM);
        float acc[4] = {0.f, 0.f, 0.f, 0.f};
        #pragma unroll 8
        for (int jq = 0; jq < 32; ++jq) {
            const float4 w4 = Wr[jq];
            #pragma unroll
            for (int rr = 0; rr < 4; ++rr) {
                const float4 h4 = *reinterpret_cast<const float4*>(
                    &as[half * 4 + rr][jq * 4]);
                acc[rr] += w4.x*h4.x + w4.y*h4.y + w4.z*h4.z + w4.w*h4.w;
            }
        }
        #pragma unroll
        for (int rr = 0; rr < 4; ++rr) {
            const int row = row0 + half * 4 + rr;
            const float y = x[(size_t)row * C_DIM + c] + acc[rr];
            ys[half * 4 + rr][c] = y;
            x1[(size_t)row * C_DIM + c] = y;
        }
    }
    __syncthreads();

    // LayerNorm on ys -> h2
    {
        const int r = t >> 5, l = t & 31;
        const float4 yv = *reinterpret_cast<const float4*>(&ys[r][l * 4]);
        float s  = yv.x + yv.y + yv.z + yv.w;
        float ss = yv.x*yv.x + yv.y*yv.y + yv.z*yv.z + yv.w*yv.w;
        #pragma unroll
        for (int m = 16; m >= 1; m >>= 1) {
            s  += __shfl_xor(s,  m);
            ss += __shfl_xor(ss, m);
        }
        const float mu  = s * (1.0f / 128.0f);
        const float var = ss * (1.0f / 128.0f) - mu * mu;
        const float inv = rsqrtf(var + LN_EPS);
        float4 hv;
        hv.x = (yv.x - mu) * inv;
        hv.y = (yv.y - mu) * inv;
        hv.z = (yv.z - mu) * inv;
        hv.w = (yv.w - mu) * inv;
        reinterpret_cast<float4*>(h2 + (size_t)(row0 + r) * C_DIM)[l] = hv;
    }
}

// ---------------------------------------------------------------------------
// K4: out = x1 + silu(h2 @ W1.T + b1) @ W2.T + b2
// ---------------------------------------------------------------------------
__global__ __launch_bounds__(256) void mlp_kernel(
    const float* __restrict__ x1, const float* __restrict__ h2,
    const float* __restrict__ W1, const float* __restrict__ b1,
    const float* __restrict__ W2, const float* __restrict__ b2,
    float* __restrict__ out)
{
    __shared__ __align__(16) float hs[8][128];
    __shared__ __align__(16) float gs[8][512];
    const int t = threadIdx.x;
    const int row0 = blockIdx.x * 8;

    {
        const int r = t >> 5, l = t & 31;
        const float4 hv = reinterpret_cast<const float4*>(
            h2 + (size_t)(row0 + r) * C_DIM)[l];
        *reinterpret_cast<float4*>(&hs[r][l * 4]) = hv;
    }
    __syncthreads();

    // phase 1: hidden cols t and t+256
    #pragma unroll
    for (int cc = 0; cc < 2; ++cc) {
        const int c = t + cc * 256;
        const float4* Wr = reinterpret_cast<const float4*>(W1 + (size_t)c * C_DIM);
        float acc[8] = {0.f,0.f,0.f,0.f,0.f,0.f,0.f,0.f};
        #pragma unroll 8
        for (int jq = 0; jq < 32; ++jq) {
            const float4 w4 = Wr[jq];
            #pragma unroll
            for (int r = 0; r < 8; ++r) {
                const float4 h4 = *reinterpret_cast<const float4*>(&hs[r][jq * 4]);
                acc[r] += w4.x*h4.x + w4.y*h4.y + w4.z*h4.z + w4.w*h4.w;
            }
        }
        const float bb = b1[c];
        #pragma unroll
        for (int r = 0; r < 8; ++r) {
            const float yv = acc[r] + bb;
            gs[r][c] = yv / (1.0f + __expf(-yv));   // silu
        }
    }
    __syncthreads();

    // phase 2: out cols
    const int c = t & 127, half = t >> 7;
    const float4* Wr2 = reinterpret_cast<const float4*>(W2 + (size_t)c * 512);
    float acc[4] = {0.f, 0.f, 0.f, 0.f};
    #pragma unroll 8
    for (int jq = 0; jq < 128; ++jq) {
        const float4 w4 = Wr2[jq];
        #pragma unroll
        for (int rr = 0; rr < 4; ++rr) {
            const float4 g4 = *reinterpret_cast<const float4*>(
                &gs[half * 4 + rr][jq * 4]);
            acc[rr] += w4.x*g4.x + w4.y*g4.y + w4.z*g4.z + w4.w*g4.w;
        }
    }
    const float bb = b2[c];
    #pragma unroll
    for (int rr = 0; rr < 4; ++rr) {
        const int row = row0 + half * 4 + rr;
        out[(size_t)row * C_DIM + c] = x1[(size_t)row * C_DIM + c] + acc[rr] + bb;
    }
}

// ---------------------------------------------------------------------------
extern "C" void kernel_launch(void* const* d_in, const int* in_sizes, int n_in,
                              void* d_out, int out_size, void* d_ws, size_t ws_size,
                              hipStream_t stream)
{
    const float* x    = (const float*)d_in[0];
    const float* pair = (const float*)d_in[1];
    const int*   bidx = (const int*)  d_in[2];
    const float* Wq   = (const float*)d_in[3];
    const float* Wk   = (const float*)d_in[4];
    const float* Wv   = (const float*)d_in[5];
    const float* Wb   = (const float*)d_in[6];
    const float* Wout = (const float*)d_in[7];
    const float* W1   = (const float*)d_in[8];
    const float* b1   = (const float*)d_in[9];
    const float* W2   = (const float*)d_in[10];
    const float* b2   = (const float*)d_in[11];
    float* out = (float*)d_out;

    char* ws = (char*)d_ws;
    const size_t mat = (size_t)N_ATOMS * C_DIM * sizeof(float);  // 1 MB
    float* q  = (float*)(ws + 0 * mat);
    float* k  = (float*)(ws + 1 * mat);
    float* v  = (float*)(ws + 2 * mat);
    float* ao = (float*)(ws + 3 * mat);
    float* x1 = (float*)(ws + 4 * mat);
    float* h2 = (float*)(ws + 5 * mat);

    hipLaunchKernelGGL(ln_qkv_kernel, dim3(N_ATOMS / 8), dim3(256), 0, stream,
                       x, Wq, Wk, Wv, q, k, v);
    hipLaunchKernelGGL(attn_kernel, dim3(N_ATOMS), dim3(128), 0, stream,
                       q, k, v, pair, bidx, Wb, ao);
    hipLaunchKernelGGL(proj_ln_kernel, dim3(N_ATOMS / 8), dim3(256), 0, stream,
                       ao, x, Wout, x1, h2);
    hipLaunchKernelGGL(mlp_kernel, dim3(N_ATOMS / 8), dim3(256), 0, stream,
                       x1, h2, W1, b1, W2, b2, out);
}

// Round 2
// 80.923 us; speedup vs baseline: 1.2321x; 1.2321x over previous
//
#include <hip/hip_runtime.h>
#include <hip/hip_bf16.h>

#define N_ATOMS 2048
#define C_DIM   128
#define C_PAIR  16
#define BLK_K   128
#define LN_EPS  1e-5f

typedef float f32x4 __attribute__((ext_vector_type(4)));

// ---------------------------------------------------------------------------
// K1: LayerNorm(x) -> h (LDS), then q/k/v = h @ W{q,k,v}.T
// 768 threads = 3 projections x 128 cols x 2 K-halves. 8 rows/block, grid 256.
// K-split: no duplicated weight reads; partial sums reduced through LDS.
// ---------------------------------------------------------------------------
__global__ __launch_bounds__(768) void ln_qkv_kernel(
    const float* __restrict__ x,
    const float* __restrict__ Wq, const float* __restrict__ Wk,
    const float* __restrict__ Wv,
    float* __restrict__ q, float* __restrict__ k, float* __restrict__ v)
{
    __shared__ __align__(16) float hs[8][128];            // 4 KB
    __shared__ __align__(16) float part[2][3][8][128];    // 24 KB
    const int t = threadIdx.x;
    const int row0 = blockIdx.x * 8;

    if (t < 256) {
        const int r = t >> 5, l = t & 31;
        const float4 xv = reinterpret_cast<const float4*>(
            x + (size_t)(row0 + r) * C_DIM)[l];
        float s  = xv.x + xv.y + xv.z + xv.w;
        float ss = xv.x*xv.x + xv.y*xv.y + xv.z*xv.z + xv.w*xv.w;
        #pragma unroll
        for (int m = 16; m >= 1; m >>= 1) {
            s  += __shfl_xor(s,  m);
            ss += __shfl_xor(ss, m);
        }
        const float mu  = s * (1.0f / 128.0f);
        const float var = ss * (1.0f / 128.0f) - mu * mu;
        const float inv = rsqrtf(var + LN_EPS);
        float4 hv;
        hv.x = (xv.x - mu) * inv;
        hv.y = (xv.y - mu) * inv;
        hv.z = (xv.z - mu) * inv;
        hv.w = (xv.w - mu) * inv;
        *reinterpret_cast<float4*>(&hs[r][l * 4]) = hv;
    }
    __syncthreads();

    {
        const int p  = t >> 8;        // 0..2 projection
        const int u  = t & 255;
        const int c  = u & 127;       // output col
        const int kh = u >> 7;        // 0..1 K-half (64 each)
        const float* Wp = (p == 0) ? Wq : (p == 1) ? Wk : Wv;
        const float4* W4 = reinterpret_cast<const float4*>(
            Wp + (size_t)c * C_DIM + kh * 64);
        float acc[8] = {0.f,0.f,0.f,0.f,0.f,0.f,0.f,0.f};
        #pragma unroll
        for (int jq = 0; jq < 16; ++jq) {
            const float4 w4 = W4[jq];
            #pragma unroll
            for (int r = 0; r < 8; ++r) {
                const float4 h4 = *reinterpret_cast<const float4*>(
                    &hs[r][kh * 64 + jq * 4]);
                acc[r] += w4.x*h4.x + w4.y*h4.y + w4.z*h4.z + w4.w*h4.w;
            }
        }
        #pragma unroll
        for (int r = 0; r < 8; ++r) part[kh][p][r][c] = acc[r];
    }
    __syncthreads();

    {
        const int p  = t >> 8;
        const int u  = t & 255;
        const int c  = u & 127;
        const int rh = u >> 7;
        float* Op = (p == 0) ? q : (p == 1) ? k : v;
        #pragma unroll
        for (int rr = 0; rr < 4; ++rr) {
            const int r = rh * 4 + rr;
            Op[(size_t)(row0 + r) * C_DIM + c] =
                part[0][p][r][c] + part[1][p][r][c];
        }
    }
}

// ---------------------------------------------------------------------------
// K2: block-sparse attention. One block (128 threads) per query row.
// Pair gather issued FIRST (HBM, zero-reuse -> nontemporal), k gather under it.
// ---------------------------------------------------------------------------
__global__ __launch_bounds__(128) void attn_kernel(
    const float* __restrict__ q, const float* __restrict__ k,
    const float* __restrict__ v, const float* __restrict__ pair,
    const int*  __restrict__ bidx, const float* __restrict__ Wb,
    float* __restrict__ attn_out)
{
    __shared__ __align__(16) float qS[128];
    __shared__ int   idxS[128];
    __shared__ float S[4][128];

    const int t   = threadIdx.x;
    const int row = blockIdx.x;

    const int j = bidx[(size_t)row * BLK_K + t];
    idxS[t] = j;
    qS[t] = q[(size_t)row * C_DIM + t];

    // --- pair bias gather: 64B contiguous from HBM, nontemporal ---
    const f32x4* pr = reinterpret_cast<const f32x4*>(
        pair + ((size_t)row * N_ATOMS + (size_t)j) * C_PAIR);
    const f32x4 p0 = __builtin_nontemporal_load(pr + 0);
    const f32x4 p1 = __builtin_nontemporal_load(pr + 1);
    const f32x4 p2 = __builtin_nontemporal_load(pr + 2);
    const f32x4 p3 = __builtin_nontemporal_load(pr + 3);
    __syncthreads();

    // --- scores for 4 heads (k rows L2-resident) ---
    const float4* kr = reinterpret_cast<const float4*>(k + (size_t)j * C_DIM);
    const float4* q4 = reinterpret_cast<const float4*>(qS);
    float sc[4];
    #pragma unroll
    for (int h = 0; h < 4; ++h) {
        float a = 0.f;
        #pragma unroll
        for (int d = 0; d < 8; ++d) {
            const float4 kk = kr[h * 8 + d];
            const float4 qq = q4[h * 8 + d];
            a += kk.x*qq.x + kk.y*qq.y + kk.z*qq.z + kk.w*qq.w;
        }
        sc[h] = a;
    }

    const float pm = (p0.x+p0.y+p0.z+p0.w + p1.x+p1.y+p1.z+p1.w +
                      p2.x+p2.y+p2.z+p2.w + p3.x+p3.y+p3.z+p3.w) * (1.0f/16.0f);
    const float scale = 0.17677669529663687f;  // 1/sqrt(32)
    #pragma unroll
    for (int h = 0; h < 4; ++h)
        S[h][t] = sc[h] * scale + pm * Wb[h];
    __syncthreads();

    // --- softmax per head (32 threads per head) ---
    {
        const int g = t >> 5, l = t & 31;
        const float v0 = S[g][l], v1 = S[g][l + 32],
                    v2 = S[g][l + 64], v3 = S[g][l + 96];
        float mx = fmaxf(fmaxf(v0, v1), fmaxf(v2, v3));
        #pragma unroll
        for (int m = 16; m >= 1; m >>= 1) mx = fmaxf(mx, __shfl_xor(mx, m));
        const float e0 = __expf(v0 - mx), e1 = __expf(v1 - mx),
                    e2 = __expf(v2 - mx), e3 = __expf(v3 - mx);
        float sm = e0 + e1 + e2 + e3;
        #pragma unroll
        for (int m = 16; m >= 1; m >>= 1) sm += __shfl_xor(sm, m);
        const float rs = 1.0f / sm;
        S[g][l]      = e0 * rs;
        S[g][l + 32] = e1 * rs;
        S[g][l + 64] = e2 * rs;
        S[g][l + 96] = e3 * rs;
    }
    __syncthreads();

    // --- PV: thread t = output dim; coalesced v reads ---
    const int hh = t >> 5;
    float acc = 0.f;
    #pragma unroll 8
    for (int b = 0; b < BLK_K; ++b) {
        acc += S[hh][b] * v[(size_t)idxS[b] * C_DIM + t];
    }
    attn_out[(size_t)row * C_DIM + t] = acc;
}

// ---------------------------------------------------------------------------
// K3: fused  x1 = x + ao@Wout.T ; h2 = LN(x1) ; out = x1 + silu(h2@W1.T+b1)@W2.T + b2
// 1024 threads, 8 rows/block, grid 256. All GEMM phases K-split (weights read
// exactly once per block), partials reduced through a shared 32KB buffer.
// ---------------------------------------------------------------------------
__global__ __launch_bounds__(1024) void proj_ln_mlp_kernel(
    const float* __restrict__ ao, const float* __restrict__ x,
    const float* __restrict__ Wout,
    const float* __restrict__ W1, const float* __restrict__ b1,
    const float* __restrict__ W2, const float* __restrict__ b2,
    float* __restrict__ out)
{
    __shared__ __align__(16) float as[8][128];        // 4 KB  attn_out rows
    __shared__ __align__(16) float ys[8][128];        // 4 KB  x1 rows
    __shared__ __align__(16) float h2s[8][128];       // 4 KB  LN(x1)
    __shared__ __align__(16) float gs[8][512];        // 16 KB silu hidden
    __shared__ __align__(16) float part[8][8][128];   // 32 KB partial sums
    float* partF = &part[0][0][0];                    // alias [2][8][512] for M1

    const int t = threadIdx.x;
    const int row0 = blockIdx.x * 8;

    // --- A: stage ao and x ---
    if (t < 256) {
        const int r = t >> 5, l = t & 31;
        const float4 av = reinterpret_cast<const float4*>(
            ao + (size_t)(row0 + r) * C_DIM)[l];
        *reinterpret_cast<float4*>(&as[r][l * 4]) = av;
    } else if (t < 512) {
        const int u = t - 256;
        const int r = u >> 5, l = u & 31;
        const float4 xv = reinterpret_cast<const float4*>(
            x + (size_t)(row0 + r) * C_DIM)[l];
        *reinterpret_cast<float4*>(&ys[r][l * 4]) = xv;
    }
    __syncthreads();

    // --- P: proj partials. 128 cols x 8 K-slices (16 floats each) ---
    {
        const int c  = t & 127;
        const int ks = t >> 7;    // 0..7
        const float4* W4 = reinterpret_cast<const float4*>(
            Wout + (size_t)c * C_DIM + ks * 16);
        float acc[8] = {0.f,0.f,0.f,0.f,0.f,0.f,0.f,0.f};
        #pragma unroll
        for (int jq = 0; jq < 4; ++jq) {
            const float4 w4 = W4[jq];
            #pragma unroll
            for (int r = 0; r < 8; ++r) {
                const float4 h4 = *reinterpret_cast<const float4*>(
                    &as[r][ks * 16 + jq * 4]);
                acc[r] += w4.x*h4.x + w4.y*h4.y + w4.z*h4.z + w4.w*h4.w;
            }
        }
        #pragma unroll
        for (int r = 0; r < 8; ++r) part[ks][r][c] = acc[r];
    }
    __syncthreads();

    // --- R1: x1 = x + sum(partials) ---
    {
        const int r = t >> 7, c = t & 127;
        float y = ys[r][c];
        #pragma unroll
        for (int ks = 0; ks < 8; ++ks) y += part[ks][r][c];
        ys[r][c] = y;
    }
    __syncthreads();

    // --- LN: h2 = LayerNorm(x1) ---
    if (t < 256) {
        const int r = t >> 5, l = t & 31;
        const float4 yv = *reinterpret_cast<const float4*>(&ys[r][l * 4]);
        float s  = yv.x + yv.y + yv.z + yv.w;
        float ss = yv.x*yv.x + yv.y*yv.y + yv.z*yv.z + yv.w*yv.w;
        #pragma unroll
        for (int m = 16; m >= 1; m >>= 1) {
            s  += __shfl_xor(s,  m);
            ss += __shfl_xor(ss, m);
        }
        const float mu  = s * (1.0f / 128.0f);
        const float var = ss * (1.0f / 128.0f) - mu * mu;
        const float inv = rsqrtf(var + LN_EPS);
        float4 hv;
        hv.x = (yv.x - mu) * inv;
        hv.y = (yv.y - mu) * inv;
        hv.z = (yv.z - mu) * inv;
        hv.w = (yv.w - mu) * inv;
        *reinterpret_cast<float4*>(&h2s[r][l * 4]) = hv;
    }
    __syncthreads();

    // --- M1: hidden partials. 512 cols x 2 K-halves (64 floats each) ---
    {
        const int c  = t & 511;
        const int kh = t >> 9;    // 0..1
        const float4* W4 = reinterpret_cast<const float4*>(
            W1 + (size_t)c * C_DIM + kh * 64);
        float acc[8] = {0.f,0.f,0.f,0.f,0.f,0.f,0.f,0.f};
        #pragma unroll
        for (int jq = 0; jq < 16; ++jq) {
            const float4 w4 = W4[jq];
            #pragma unroll
            for (int r = 0; r < 8; ++r) {
                const float4 h4 = *reinterpret_cast<const float4*>(
                    &h2s[r][kh * 64 + jq * 4]);
                acc[r] += w4.x*h4.x + w4.y*h4.y + w4.z*h4.z + w4.w*h4.w;
            }
        }
        #pragma unroll
        for (int r = 0; r < 8; ++r) partF[((kh << 3) + r) * 512 + c] = acc[r];
    }
    __syncthreads();

    // --- R2: gs = silu(p0 + p1 + b1) ---
    #pragma unroll
    for (int rep = 0; rep < 4; ++rep) {
        const int slot = t + rep * 1024;
        const int r = slot >> 9, c = slot & 511;
        const float g = partF[r * 512 + c] + partF[(8 + r) * 512 + c] + b1[c];
        gs[r][c] = g / (1.0f + __expf(-g));
    }
    __syncthreads();

    // --- M2: out partials. 128 cols x 8 K-slices (64 floats each, K=512) ---
    {
        const int c  = t & 127;
        const int ks = t >> 7;    // 0..7
        const float4* W4 = reinterpret_cast<const float4*>(
            W2 + (size_t)c * 512 + ks * 64);
        float acc[8] = {0.f,0.f,0.f,0.f,0.f,0.f,0.f,0.f};
        #pragma unroll
        for (int jq = 0; jq < 16; ++jq) {
            const float4 w4 = W4[jq];
            #pragma unroll
            for (int r = 0; r < 8; ++r) {
                const float4 g4 = *reinterpret_cast<const float4*>(
                    &gs[r][ks * 64 + jq * 4]);
                acc[r] += w4.x*g4.x + w4.y*g4.y + w4.z*g4.z + w4.w*g4.w;
            }
        }
        #pragma unroll
        for (int r = 0; r < 8; ++r) part[ks][r][c] = acc[r];
    }
    __syncthreads();

    // --- R3: out = x1 + b2 + sum(partials) ---
    {
        const int r = t >> 7, c = t & 127;
        float o = ys[r][c] + b2[c];
        #pragma unroll
        for (int ks = 0; ks < 8; ++ks) o += part[ks][r][c];
        out[(size_t)(row0 + r) * C_DIM + c] = o;
    }
}

// ---------------------------------------------------------------------------
extern "C" void kernel_launch(void* const* d_in, const int* in_sizes, int n_in,
                              void* d_out, int out_size, void* d_ws, size_t ws_size,
                              hipStream_t stream)
{
    const float* x    = (const float*)d_in[0];
    const float* pair = (const float*)d_in[1];
    const int*   bidx = (const int*)  d_in[2];
    const float* Wq   = (const float*)d_in[3];
    const float* Wk   = (const float*)d_in[4];
    const float* Wv   = (const float*)d_in[5];
    const float* Wb   = (const float*)d_in[6];
    const float* Wout = (const float*)d_in[7];
    const float* W1   = (const float*)d_in[8];
    const float* b1   = (const float*)d_in[9];
    const float* W2   = (const float*)d_in[10];
    const float* b2   = (const float*)d_in[11];
    float* out = (float*)d_out;

    char* ws = (char*)d_ws;
    const size_t mat = (size_t)N_ATOMS * C_DIM * sizeof(float);  // 1 MB
    float* q  = (float*)(ws + 0 * mat);
    float* k  = (float*)(ws + 1 * mat);
    float* v  = (float*)(ws + 2 * mat);
    float* ao = (float*)(ws + 3 * mat);

    hipLaunchKernelGGL(ln_qkv_kernel, dim3(N_ATOMS / 8), dim3(768), 0, stream,
                       x, Wq, Wk, Wv, q, k, v);
    hipLaunchKernelGGL(attn_kernel, dim3(N_ATOMS), dim3(128), 0, stream,
                       q, k, v, pair, bidx, Wb, ao);
    hipLaunchKernelGGL(proj_ln_mlp_kernel, dim3(N_ATOMS / 8), dim3(1024), 0, stream,
                       ao, x, Wout, W1, b1, W2, b2, out);
}

// Round 3
// 67.776 us; speedup vs baseline: 1.4711x; 1.1940x over previous
//
#include <hip/hip_runtime.h>
#include <hip/hip_bf16.h>

#define N_ATOMS 2048
#define C_DIM   128
#define C_PAIR  16
#define BLK_K   128
#define LN_EPS  1e-5f

typedef float f32x4 __attribute__((ext_vector_type(4)));

// ---------------------------------------------------------------------------
// K1: LayerNorm(x) -> h (LDS), then q/k/v = h @ W{q,k,v}.T
// 768 threads = 3 projections x 128 cols x 2 K-halves. 8 rows/block, grid 256.
// ---------------------------------------------------------------------------
__global__ __launch_bounds__(768) void ln_qkv_kernel(
    const float* __restrict__ x,
    const float* __restrict__ Wq, const float* __restrict__ Wk,
    const float* __restrict__ Wv,
    float* __restrict__ q, float* __restrict__ k, float* __restrict__ v)
{
    __shared__ __align__(16) float hs[8][128];            // 4 KB
    __shared__ __align__(16) float part[2][3][8][128];    // 24 KB
    const int t = threadIdx.x;
    const int row0 = blockIdx.x * 8;

    if (t < 256) {
        const int r = t >> 5, l = t & 31;
        const float4 xv = reinterpret_cast<const float4*>(
            x + (size_t)(row0 + r) * C_DIM)[l];
        float s  = xv.x + xv.y + xv.z + xv.w;
        float ss = xv.x*xv.x + xv.y*xv.y + xv.z*xv.z + xv.w*xv.w;
        #pragma unroll
        for (int m = 16; m >= 1; m >>= 1) {
            s  += __shfl_xor(s,  m);
            ss += __shfl_xor(ss, m);
        }
        const float mu  = s * (1.0f / 128.0f);
        const float var = ss * (1.0f / 128.0f) - mu * mu;
        const float inv = rsqrtf(var + LN_EPS);
        float4 hv;
        hv.x = (xv.x - mu) * inv;
        hv.y = (xv.y - mu) * inv;
        hv.z = (xv.z - mu) * inv;
        hv.w = (xv.w - mu) * inv;
        *reinterpret_cast<float4*>(&hs[r][l * 4]) = hv;
    }
    __syncthreads();

    {
        const int p  = t >> 8;        // 0..2 projection
        const int u  = t & 255;
        const int c  = u & 127;       // output col
        const int kh = u >> 7;        // 0..1 K-half (64 each)
        const float* Wp = (p == 0) ? Wq : (p == 1) ? Wk : Wv;
        const float4* W4 = reinterpret_cast<const float4*>(
            Wp + (size_t)c * C_DIM + kh * 64);
        float acc[8] = {0.f,0.f,0.f,0.f,0.f,0.f,0.f,0.f};
        #pragma unroll
        for (int jq = 0; jq < 16; ++jq) {
            const float4 w4 = W4[jq];
            #pragma unroll
            for (int r = 0; r < 8; ++r) {
                const float4 h4 = *reinterpret_cast<const float4*>(
                    &hs[r][kh * 64 + jq * 4]);
                acc[r] += w4.x*h4.x + w4.y*h4.y + w4.z*h4.z + w4.w*h4.w;
            }
        }
        #pragma unroll
        for (int r = 0; r < 8; ++r) part[kh][p][r][c] = acc[r];
    }
    __syncthreads();

    {
        const int p  = t >> 8;
        const int u  = t & 255;
        const int c  = u & 127;
        const int rh = u >> 7;
        float* Op = (p == 0) ? q : (p == 1) ? k : v;
        #pragma unroll
        for (int rr = 0; rr < 4; ++rr) {
            const int r = rh * 4 + rr;
            Op[(size_t)(row0 + r) * C_DIM + c] =
                part[0][p][r][c] + part[1][p][r][c];
        }
    }
}

// ---------------------------------------------------------------------------
// K2: fused attention + proj + LN + MLP. 1024 threads, 8 query rows per block,
// grid 256 (1 block/CU, 16 waves). Row-local after QKV, so fully fusable.
// ---------------------------------------------------------------------------
__global__ __launch_bounds__(1024) void attn_mlp_kernel(
    const float* __restrict__ q, const float* __restrict__ k,
    const float* __restrict__ v, const float* __restrict__ pair,
    const int*  __restrict__ bidx, const float* __restrict__ Wb,
    const float* __restrict__ x,  const float* __restrict__ Wout,
    const float* __restrict__ W1, const float* __restrict__ b1,
    const float* __restrict__ W2, const float* __restrict__ b2,
    float* __restrict__ out)
{
    __shared__ __align__(16) float qS[8][128];      // 4 KB
    __shared__ __align__(16) int   idxS[8][128];    // 4 KB
    __shared__ __align__(16) float S[8][4][128];    // 16 KB
    __shared__ __align__(16) float aoS[8][128];     // 4 KB
    __shared__ __align__(16) float ys[8][128];      // 4 KB  x1 rows
    __shared__ __align__(16) float h2s[8][128];     // 4 KB
    __shared__ __align__(16) float gs[8][512];      // 16 KB
    __shared__ __align__(16) float part[8][8][128]; // 32 KB
    float* partF = &part[0][0][0];                  // alias [16][512] for M1

    const int t = threadIdx.x;
    const int row0 = blockIdx.x * 8;
    const int r = t >> 7;          // local row 0..7
    const int u = t & 127;         // key slot / dim
    const int row = row0 + r;

    // --- A: stage q, idx, x; issue pair gather (HBM, nontemporal) ---
    const int j = bidx[(size_t)row * BLK_K + u];
    idxS[r][u] = j;
    qS[r][u] = q[(size_t)row * C_DIM + u];
    if (t < 256) {
        const int r2 = t >> 5, l = t & 31;
        const float4 xv = reinterpret_cast<const float4*>(
            x + (size_t)(row0 + r2) * C_DIM)[l];
        *reinterpret_cast<float4*>(&ys[r2][l * 4]) = xv;
    }
    const f32x4* pr = reinterpret_cast<const f32x4*>(
        pair + ((size_t)row * N_ATOMS + (size_t)j) * C_PAIR);
    const f32x4 p0 = __builtin_nontemporal_load(pr + 0);
    const f32x4 p1 = __builtin_nontemporal_load(pr + 1);
    const f32x4 p2 = __builtin_nontemporal_load(pr + 2);
    const f32x4 p3 = __builtin_nontemporal_load(pr + 3);
    __syncthreads();

    // --- scores: thread (r, u) dots q row r with k[j] for 4 heads ---
    {
        const float4* kr = reinterpret_cast<const float4*>(k + (size_t)j * C_DIM);
        const float4* q4 = reinterpret_cast<const float4*>(&qS[r][0]);
        float sc[4];
        #pragma unroll
        for (int h = 0; h < 4; ++h) {
            float a = 0.f;
            #pragma unroll
            for (int d = 0; d < 8; ++d) {
                const float4 kk = kr[h * 8 + d];
                const float4 qq = q4[h * 8 + d];
                a += kk.x*qq.x + kk.y*qq.y + kk.z*qq.z + kk.w*qq.w;
            }
            sc[h] = a;
        }
        const float pm = (p0.x+p0.y+p0.z+p0.w + p1.x+p1.y+p1.z+p1.w +
                          p2.x+p2.y+p2.z+p2.w + p3.x+p3.y+p3.z+p3.w) * (1.0f/16.0f);
        const float scale = 0.17677669529663687f;  // 1/sqrt(32)
        #pragma unroll
        for (int h = 0; h < 4; ++h)
            S[r][h][u] = sc[h] * scale + pm * Wb[h];
    }
    __syncthreads();

    // --- softmax per (row, head): 32 lanes per head ---
    {
        const int g = u >> 5, l = u & 31;
        const float v0 = S[r][g][l],      v1 = S[r][g][l + 32],
                    v2 = S[r][g][l + 64], v3 = S[r][g][l + 96];
        float mx = fmaxf(fmaxf(v0, v1), fmaxf(v2, v3));
        #pragma unroll
        for (int m = 16; m >= 1; m >>= 1) mx = fmaxf(mx, __shfl_xor(mx, m));
        const float e0 = __expf(v0 - mx), e1 = __expf(v1 - mx),
                    e2 = __expf(v2 - mx), e3 = __expf(v3 - mx);
        float sm = e0 + e1 + e2 + e3;
        #pragma unroll
        for (int m = 16; m >= 1; m >>= 1) sm += __shfl_xor(sm, m);
        const float rs = 1.0f / sm;
        S[r][g][l]      = e0 * rs;
        S[r][g][l + 32] = e1 * rs;
        S[r][g][l + 64] = e2 * rs;
        S[r][g][l + 96] = e3 * rs;
    }
    __syncthreads();

    // --- PV: thread (r, dim u); vectorized S/idx reads; coalesced v ---
    {
        const int hh = u >> 5;
        const float4* Sv = reinterpret_cast<const float4*>(&S[r][hh][0]);
        const int4*   iv = reinterpret_cast<const int4*>(&idxS[r][0]);
        float acc = 0.f;
        #pragma unroll 8
        for (int bq = 0; bq < 32; ++bq) {
            const float4 s4 = Sv[bq];
            const int4   j4 = iv[bq];
            acc += s4.x * v[(size_t)j4.x * C_DIM + u];
            acc += s4.y * v[(size_t)j4.y * C_DIM + u];
            acc += s4.z * v[(size_t)j4.z * C_DIM + u];
            acc += s4.w * v[(size_t)j4.w * C_DIM + u];
        }
        aoS[r][u] = acc;
    }
    __syncthreads();

    // --- P: proj partials. 128 cols x 8 K-slices (16 floats each) ---
    {
        const int c  = t & 127;
        const int ks = t >> 7;
        const float4* W4 = reinterpret_cast<const float4*>(
            Wout + (size_t)c * C_DIM + ks * 16);
        float acc[8] = {0.f,0.f,0.f,0.f,0.f,0.f,0.f,0.f};
        #pragma unroll
        for (int jq = 0; jq < 4; ++jq) {
            const float4 w4 = W4[jq];
            #pragma unroll
            for (int rr = 0; rr < 8; ++rr) {
                const float4 h4 = *reinterpret_cast<const float4*>(
                    &aoS[rr][ks * 16 + jq * 4]);
                acc[rr] += w4.x*h4.x + w4.y*h4.y + w4.z*h4.z + w4.w*h4.w;
            }
        }
        #pragma unroll
        for (int rr = 0; rr < 8; ++rr) part[ks][rr][c] = acc[rr];
    }
    __syncthreads();

    // --- R1: x1 = x + sum(partials) ---
    {
        const int rr = t >> 7, c = t & 127;
        float y = ys[rr][c];
        #pragma unroll
        for (int ks = 0; ks < 8; ++ks) y += part[ks][rr][c];
        ys[rr][c] = y;
    }
    __syncthreads();

    // --- LN: h2 = LayerNorm(x1) ---
    if (t < 256) {
        const int rr = t >> 5, l = t & 31;
        const float4 yv = *reinterpret_cast<const float4*>(&ys[rr][l * 4]);
        float s  = yv.x + yv.y + yv.z + yv.w;
        float ss = yv.x*yv.x + yv.y*yv.y + yv.z*yv.z + yv.w*yv.w;
        #pragma unroll
        for (int m = 16; m >= 1; m >>= 1) {
            s  += __shfl_xor(s,  m);
            ss += __shfl_xor(ss, m);
        }
        const float mu  = s * (1.0f / 128.0f);
        const float var = ss * (1.0f / 128.0f) - mu * mu;
        const float inv = rsqrtf(var + LN_EPS);
        float4 hv;
        hv.x = (yv.x - mu) * inv;
        hv.y = (yv.y - mu) * inv;
        hv.z = (yv.z - mu) * inv;
        hv.w = (yv.w - mu) * inv;
        *reinterpret_cast<float4*>(&h2s[rr][l * 4]) = hv;
    }
    __syncthreads();

    // --- M1: hidden partials. 512 cols x 2 K-halves ---
    {
        const int c  = t & 511;
        const int kh = t >> 9;
        const float4* W4 = reinterpret_cast<const float4*>(
            W1 + (size_t)c * C_DIM + kh * 64);
        float acc[8] = {0.f,0.f,0.f,0.f,0.f,0.f,0.f,0.f};
        #pragma unroll
        for (int jq = 0; jq < 16; ++jq) {
            const float4 w4 = W4[jq];
            #pragma unroll
            for (int rr = 0; rr < 8; ++rr) {
                const float4 h4 = *reinterpret_cast<const float4*>(
                    &h2s[rr][kh * 64 + jq * 4]);
                acc[rr] += w4.x*h4.x + w4.y*h4.y + w4.z*h4.z + w4.w*h4.w;
            }
        }
        #pragma unroll
        for (int rr = 0; rr < 8; ++rr) partF[((kh << 3) + rr) * 512 + c] = acc[rr];
    }
    __syncthreads();

    // --- R2: gs = silu(p0 + p1 + b1) ---
    #pragma unroll
    for (int rep = 0; rep < 4; ++rep) {
        const int slot = t + rep * 1024;
        const int rr = slot >> 9, c = slot & 511;
        const float g = partF[rr * 512 + c] + partF[(8 + rr) * 512 + c] + b1[c];
        gs[rr][c] = g / (1.0f + __expf(-g));
    }
    __syncthreads();

    // --- M2: out partials. 128 cols x 8 K-slices (64 floats each, K=512) ---
    {
        const int c  = t & 127;
        const int ks = t >> 7;
        const float4* W4 = reinterpret_cast<const float4*>(
            W2 + (size_t)c * 512 + ks * 64);
        float acc[8] = {0.f,0.f,0.f,0.f,0.f,0.f,0.f,0.f};
        #pragma unroll
        for (int jq = 0; jq < 16; ++jq) {
            const float4 w4 = W4[jq];
            #pragma unroll
            for (int rr = 0; rr < 8; ++rr) {
                const float4 g4 = *reinterpret_cast<const float4*>(
                    &gs[rr][ks * 64 + jq * 4]);
                acc[rr] += w4.x*g4.x + w4.y*g4.y + w4.z*g4.z + w4.w*g4.w;
            }
        }
        #pragma unroll
        for (int rr = 0; rr < 8; ++rr) part[ks][rr][c] = acc[rr];
    }
    __syncthreads();

    // --- R3: out = x1 + b2 + sum(partials) ---
    {
        const int rr = t >> 7, c = t & 127;
        float o = ys[rr][c] + b2[c];
        #pragma unroll
        for (int ks = 0; ks < 8; ++ks) o += part[ks][rr][c];
        out[(size_t)(row0 + rr) * C_DIM + c] = o;
    }
}

// ---------------------------------------------------------------------------
extern "C" void kernel_launch(void* const* d_in, const int* in_sizes, int n_in,
                              void* d_out, int out_size, void* d_ws, size_t ws_size,
                              hipStream_t stream)
{
    const float* x    = (const float*)d_in[0];
    const float* pair = (const float*)d_in[1];
    const int*   bidx = (const int*)  d_in[2];
    const float* Wq   = (const float*)d_in[3];
    const float* Wk   = (const float*)d_in[4];
    const float* Wv   = (const float*)d_in[5];
    const float* Wb   = (const float*)d_in[6];
    const float* Wout = (const float*)d_in[7];
    const float* W1   = (const float*)d_in[8];
    const float* b1   = (const float*)d_in[9];
    const float* W2   = (const float*)d_in[10];
    const float* b2   = (const float*)d_in[11];
    float* out = (float*)d_out;

    char* ws = (char*)d_ws;
    const size_t mat = (size_t)N_ATOMS * C_DIM * sizeof(float);  // 1 MB
    float* q  = (float*)(ws + 0 * mat);
    float* k  = (float*)(ws + 1 * mat);
    float* v  = (float*)(ws + 2 * mat);

    hipLaunchKernelGGL(ln_qkv_kernel, dim3(N_ATOMS / 8), dim3(768), 0, stream,
                       x, Wq, Wk, Wv, q, k, v);
    hipLaunchKernelGGL(attn_mlp_kernel, dim3(N_ATOMS / 8), dim3(1024), 0, stream,
                       q, k, v, pair, bidx, Wb, x, Wout, W1, b1, W2, b2, out);
}

// Round 4
// 59.059 us; speedup vs baseline: 1.6882x; 1.1476x over previous
//
#include <hip/hip_runtime.h>
#include <hip/hip_bf16.h>

#define N_ATOMS 2048
#define C_DIM   128
#define C_PAIR  16
#define BLK_K   128
#define LN_EPS  1e-5f

typedef float f32x4 __attribute__((ext_vector_type(4)));

__device__ __forceinline__ float bf_lo(unsigned int p) {
    union { unsigned int i; float f; } u; u.i = p << 16; return u.f;
}
__device__ __forceinline__ float bf_hi(unsigned int p) {
    union { unsigned int i; float f; } u; u.i = p & 0xffff0000u; return u.f;
}
__device__ __forceinline__ float bf2f(unsigned short s) {
    union { unsigned int i; float f; } u; u.i = ((unsigned int)s) << 16; return u.f;
}
__device__ __forceinline__ unsigned short f2bf(float f) {
    union { float f; unsigned int i; } u; u.f = f;
    const unsigned int r = u.i + 0x7fffu + ((u.i >> 16) & 1u);  // round-nearest-even
    return (unsigned short)(r >> 16);
}

// ---------------------------------------------------------------------------
// K1: LayerNorm(x) -> h (LDS), then q = h@Wq.T (f32), k/v = h@W.T (bf16)
// 768 threads = 3 projections x 128 cols x 2 K-halves. 8 rows/block, grid 256.
// ---------------------------------------------------------------------------
__global__ __launch_bounds__(768) void ln_qkv_kernel(
    const float* __restrict__ x,
    const float* __restrict__ Wq, const float* __restrict__ Wk,
    const float* __restrict__ Wv,
    float* __restrict__ q,
    unsigned short* __restrict__ kb, unsigned short* __restrict__ vb)
{
    __shared__ __align__(16) float hs[8][128];            // 4 KB
    __shared__ __align__(16) float part[2][3][8][128];    // 24 KB
    const int t = threadIdx.x;
    const int row0 = blockIdx.x * 8;

    if (t < 256) {
        const int r = t >> 5, l = t & 31;
        const float4 xv = reinterpret_cast<const float4*>(
            x + (size_t)(row0 + r) * C_DIM)[l];
        float s  = xv.x + xv.y + xv.z + xv.w;
        float ss = xv.x*xv.x + xv.y*xv.y + xv.z*xv.z + xv.w*xv.w;
        #pragma unroll
        for (int m = 16; m >= 1; m >>= 1) {
            s  += __shfl_xor(s,  m);
            ss += __shfl_xor(ss, m);
        }
        const float mu  = s * (1.0f / 128.0f);
        const float var = ss * (1.0f / 128.0f) - mu * mu;
        const float inv = rsqrtf(var + LN_EPS);
        float4 hv;
        hv.x = (xv.x - mu) * inv;
        hv.y = (xv.y - mu) * inv;
        hv.z = (xv.z - mu) * inv;
        hv.w = (xv.w - mu) * inv;
        *reinterpret_cast<float4*>(&hs[r][l * 4]) = hv;
    }
    __syncthreads();

    {
        const int p  = t >> 8;        // 0..2 projection
        const int u  = t & 255;
        const int c  = u & 127;       // output col
        const int kh = u >> 7;        // 0..1 K-half (64 each)
        const float* Wp = (p == 0) ? Wq : (p == 1) ? Wk : Wv;
        const float4* W4 = reinterpret_cast<const float4*>(
            Wp + (size_t)c * C_DIM + kh * 64);
        float acc[8] = {0.f,0.f,0.f,0.f,0.f,0.f,0.f,0.f};
        #pragma unroll
        for (int jq = 0; jq < 16; ++jq) {
            const float4 w4 = W4[jq];
            #pragma unroll
            for (int r = 0; r < 8; ++r) {
                const float4 h4 = *reinterpret_cast<const float4*>(
                    &hs[r][kh * 64 + jq * 4]);
                acc[r] += w4.x*h4.x + w4.y*h4.y + w4.z*h4.z + w4.w*h4.w;
            }
        }
        #pragma unroll
        for (int r = 0; r < 8; ++r) part[kh][p][r][c] = acc[r];
    }
    __syncthreads();

    {
        const int p  = t >> 8;
        const int u  = t & 255;
        const int c  = u & 127;
        const int rh = u >> 7;
        #pragma unroll
        for (int rr = 0; rr < 4; ++rr) {
            const int r = rh * 4 + rr;
            const float val = part[0][p][r][c] + part[1][p][r][c];
            const size_t off = (size_t)(row0 + r) * C_DIM + c;
            if (p == 0)      q[off]  = val;
            else if (p == 1) kb[off] = f2bf(val);
            else             vb[off] = f2bf(val);
        }
    }
}

// ---------------------------------------------------------------------------
// K2: fused attention + proj + LN + MLP. 1024 threads, 8 query rows per block,
// grid 256. k/v gathered as bf16 (half the L3 gather bytes of f32).
// ---------------------------------------------------------------------------
__global__ __launch_bounds__(1024) void attn_mlp_kernel(
    const float* __restrict__ q, const unsigned short* __restrict__ kb,
    const unsigned short* __restrict__ vb, const float* __restrict__ pair,
    const int*  __restrict__ bidx, const float* __restrict__ Wb,
    const float* __restrict__ x,  const float* __restrict__ Wout,
    const float* __restrict__ W1, const float* __restrict__ b1,
    const float* __restrict__ W2, const float* __restrict__ b2,
    float* __restrict__ out)
{
    __shared__ __align__(16) float qS[8][128];      // 4 KB
    __shared__ __align__(16) int   idxS[8][128];    // 4 KB
    __shared__ __align__(16) float S[8][4][128];    // 16 KB
    __shared__ __align__(16) float aoS[8][128];     // 4 KB
    __shared__ __align__(16) float ys[8][128];      // 4 KB  x1 rows
    __shared__ __align__(16) float h2s[8][128];     // 4 KB
    __shared__ __align__(16) float gs[8][512];      // 16 KB
    __shared__ __align__(16) float part[8][8][128]; // 32 KB
    float* partF = &part[0][0][0];                  // alias [16][512] for M1

    const int t = threadIdx.x;
    const int row0 = blockIdx.x * 8;
    const int r = t >> 7;          // local row 0..7
    const int u = t & 127;         // key slot / dim
    const int row = row0 + r;

    // --- A: stage q, idx, x; issue pair gather (HBM, nontemporal) ---
    const int j = bidx[(size_t)row * BLK_K + u];
    idxS[r][u] = j;
    qS[r][u] = q[(size_t)row * C_DIM + u];
    if (t < 256) {
        const int r2 = t >> 5, l = t & 31;
        const float4 xv = reinterpret_cast<const float4*>(
            x + (size_t)(row0 + r2) * C_DIM)[l];
        *reinterpret_cast<float4*>(&ys[r2][l * 4]) = xv;
    }
    const f32x4* pr = reinterpret_cast<const f32x4*>(
        pair + ((size_t)row * N_ATOMS + (size_t)j) * C_PAIR);
    const f32x4 p0 = __builtin_nontemporal_load(pr + 0);
    const f32x4 p1 = __builtin_nontemporal_load(pr + 1);
    const f32x4 p2 = __builtin_nontemporal_load(pr + 2);
    const f32x4 p3 = __builtin_nontemporal_load(pr + 3);
    __syncthreads();

    // --- scores: thread (r, u) dots q row r with bf16 k[j] for 4 heads ---
    {
        const uint4* kr = reinterpret_cast<const uint4*>(kb + (size_t)j * C_DIM);
        const float4* q4 = reinterpret_cast<const float4*>(&qS[r][0]);
        float sc[4];
        #pragma unroll
        for (int h = 0; h < 4; ++h) {
            float a = 0.f;
            #pragma unroll
            for (int d = 0; d < 4; ++d) {
                const uint4  kk = kr[h * 4 + d];
                const float4 qa = q4[h * 8 + d * 2];
                const float4 qc = q4[h * 8 + d * 2 + 1];
                a += bf_lo(kk.x)*qa.x + bf_hi(kk.x)*qa.y
                   + bf_lo(kk.y)*qa.z + bf_hi(kk.y)*qa.w;
                a += bf_lo(kk.z)*qc.x + bf_hi(kk.z)*qc.y
                   + bf_lo(kk.w)*qc.z + bf_hi(kk.w)*qc.w;
            }
            sc[h] = a;
        }
        const float pm = (p0.x+p0.y+p0.z+p0.w + p1.x+p1.y+p1.z+p1.w +
                          p2.x+p2.y+p2.z+p2.w + p3.x+p3.y+p3.z+p3.w) * (1.0f/16.0f);
        const float scale = 0.17677669529663687f;  // 1/sqrt(32)
        #pragma unroll
        for (int h = 0; h < 4; ++h)
            S[r][h][u] = sc[h] * scale + pm * Wb[h];
    }
    __syncthreads();

    // --- softmax per (row, head): 32 lanes per head ---
    {
        const int g = u >> 5, l = u & 31;
        const float v0 = S[r][g][l],      v1 = S[r][g][l + 32],
                    v2 = S[r][g][l + 64], v3 = S[r][g][l + 96];
        float mx = fmaxf(fmaxf(v0, v1), fmaxf(v2, v3));
        #pragma unroll
        for (int m = 16; m >= 1; m >>= 1) mx = fmaxf(mx, __shfl_xor(mx, m));
        const float e0 = __expf(v0 - mx), e1 = __expf(v1 - mx),
                    e2 = __expf(v2 - mx), e3 = __expf(v3 - mx);
        float sm = e0 + e1 + e2 + e3;
        #pragma unroll
        for (int m = 16; m >= 1; m >>= 1) sm += __shfl_xor(sm, m);
        const float rs = 1.0f / sm;
        S[r][g][l]      = e0 * rs;
        S[r][g][l + 32] = e1 * rs;
        S[r][g][l + 64] = e2 * rs;
        S[r][g][l + 96] = e3 * rs;
    }
    __syncthreads();

    // --- PV: thread (r, dim u); vectorized S/idx reads; coalesced bf16 v ---
    {
        const int hh = u >> 5;
        const float4* Sv = reinterpret_cast<const float4*>(&S[r][hh][0]);
        const int4*   iv = reinterpret_cast<const int4*>(&idxS[r][0]);
        float acc = 0.f;
        #pragma unroll 8
        for (int bq = 0; bq < 32; ++bq) {
            const float4 s4 = Sv[bq];
            const int4   j4 = iv[bq];
            acc += s4.x * bf2f(vb[(size_t)j4.x * C_DIM + u]);
            acc += s4.y * bf2f(vb[(size_t)j4.y * C_DIM + u]);
            acc += s4.z * bf2f(vb[(size_t)j4.z * C_DIM + u]);
            acc += s4.w * bf2f(vb[(size_t)j4.w * C_DIM + u]);
        }
        aoS[r][u] = acc;
    }
    __syncthreads();

    // --- P: proj partials. 128 cols x 8 K-slices (16 floats each) ---
    {
        const int c  = t & 127;
        const int ks = t >> 7;
        const float4* W4 = reinterpret_cast<const float4*>(
            Wout + (size_t)c * C_DIM + ks * 16);
        float acc[8] = {0.f,0.f,0.f,0.f,0.f,0.f,0.f,0.f};
        #pragma unroll
        for (int jq = 0; jq < 4; ++jq) {
            const float4 w4 = W4[jq];
            #pragma unroll
            for (int rr = 0; rr < 8; ++rr) {
                const float4 h4 = *reinterpret_cast<const float4*>(
                    &aoS[rr][ks * 16 + jq * 4]);
                acc[rr] += w4.x*h4.x + w4.y*h4.y + w4.z*h4.z + w4.w*h4.w;
            }
        }
        #pragma unroll
        for (int rr = 0; rr < 8; ++rr) part[ks][rr][c] = acc[rr];
    }
    __syncthreads();

    // --- R1: x1 = x + sum(partials) ---
    {
        const int rr = t >> 7, c = t & 127;
        float y = ys[rr][c];
        #pragma unroll
        for (int ks = 0; ks < 8; ++ks) y += part[ks][rr][c];
        ys[rr][c] = y;
    }
    __syncthreads();

    // --- LN: h2 = LayerNorm(x1) ---
    if (t < 256) {
        const int rr = t >> 5, l = t & 31;
        const float4 yv = *reinterpret_cast<const float4*>(&ys[rr][l * 4]);
        float s  = yv.x + yv.y + yv.z + yv.w;
        float ss = yv.x*yv.x + yv.y*yv.y + yv.z*yv.z + yv.w*yv.w;
        #pragma unroll
        for (int m = 16; m >= 1; m >>= 1) {
            s  += __shfl_xor(s,  m);
            ss += __shfl_xor(ss, m);
        }
        const float mu  = s * (1.0f / 128.0f);
        const float var = ss * (1.0f / 128.0f) - mu * mu;
        const float inv = rsqrtf(var + LN_EPS);
        float4 hv;
        hv.x = (yv.x - mu) * inv;
        hv.y = (yv.y - mu) * inv;
        hv.z = (yv.z - mu) * inv;
        hv.w = (yv.w - mu) * inv;
        *reinterpret_cast<float4*>(&h2s[rr][l * 4]) = hv;
    }
    __syncthreads();

    // --- M1: hidden partials. 512 cols x 2 K-halves ---
    {
        const int c  = t & 511;
        const int kh = t >> 9;
        const float4* W4 = reinterpret_cast<const float4*>(
            W1 + (size_t)c * C_DIM + kh * 64);
        float acc[8] = {0.f,0.f,0.f,0.f,0.f,0.f,0.f,0.f};
        #pragma unroll
        for (int jq = 0; jq < 16; ++jq) {
            const float4 w4 = W4[jq];
            #pragma unroll
            for (int rr = 0; rr < 8; ++rr) {
                const float4 h4 = *reinterpret_cast<const float4*>(
                    &h2s[rr][kh * 64 + jq * 4]);
                acc[rr] += w4.x*h4.x + w4.y*h4.y + w4.z*h4.z + w4.w*h4.w;
            }
        }
        #pragma unroll
        for (int rr = 0; rr < 8; ++rr) partF[((kh << 3) + rr) * 512 + c] = acc[rr];
    }
    __syncthreads();

    // --- R2: gs = silu(p0 + p1 + b1) ---
    #pragma unroll
    for (int rep = 0; rep < 4; ++rep) {
        const int slot = t + rep * 1024;
        const int rr = slot >> 9, c = slot & 511;
        const float g = partF[rr * 512 + c] + partF[(8 + rr) * 512 + c] + b1[c];
        gs[rr][c] = g / (1.0f + __expf(-g));
    }
    __syncthreads();

    // --- M2: out partials. 128 cols x 8 K-slices (64 floats each, K=512) ---
    {
        const int c  = t & 127;
        const int ks = t >> 7;
        const float4* W4 = reinterpret_cast<const float4*>(
            W2 + (size_t)c * 512 + ks * 64);
        float acc[8] = {0.f,0.f,0.f,0.f,0.f,0.f,0.f,0.f};
        #pragma unroll
        for (int jq = 0; jq < 16; ++jq) {
            const float4 w4 = W4[jq];
            #pragma unroll
            for (int rr = 0; rr < 8; ++rr) {
                const float4 g4 = *reinterpret_cast<const float4*>(
                    &gs[rr][ks * 64 + jq * 4]);
                acc[rr] += w4.x*g4.x + w4.y*g4.y + w4.z*g4.z + w4.w*g4.w;
            }
        }
        #pragma unroll
        for (int rr = 0; rr < 8; ++rr) part[ks][rr][c] = acc[rr];
    }
    __syncthreads();

    // --- R3: out = x1 + b2 + sum(partials) ---
    {
        const int rr = t >> 7, c = t & 127;
        float o = ys[rr][c] + b2[c];
        #pragma unroll
        for (int ks = 0; ks < 8; ++ks) o += part[ks][rr][c];
        out[(size_t)(row0 + rr) * C_DIM + c] = o;
    }
}

// ---------------------------------------------------------------------------
extern "C" void kernel_launch(void* const* d_in, const int* in_sizes, int n_in,
                              void* d_out, int out_size, void* d_ws, size_t ws_size,
                              hipStream_t stream)
{
    const float* x    = (const float*)d_in[0];
    const float* pair = (const float*)d_in[1];
    const int*   bidx = (const int*)  d_in[2];
    const float* Wq   = (const float*)d_in[3];
    const float* Wk   = (const float*)d_in[4];
    const float* Wv   = (const float*)d_in[5];
    const float* Wb   = (const float*)d_in[6];
    const float* Wout = (const float*)d_in[7];
    const float* W1   = (const float*)d_in[8];
    const float* b1   = (const float*)d_in[9];
    const float* W2   = (const float*)d_in[10];
    const float* b2   = (const float*)d_in[11];
    float* out = (float*)d_out;

    char* ws = (char*)d_ws;
    float*          q  = (float*)ws;                          // 1 MB
    unsigned short* kb = (unsigned short*)(ws + (1 << 20));   // 0.5 MB
    unsigned short* vb = (unsigned short*)(ws + (1 << 20) + (1 << 19));

    hipLaunchKernelGGL(ln_qkv_kernel, dim3(N_ATOMS / 8), dim3(768), 0, stream,
                       x, Wq, Wk, Wv, q, kb, vb);
    hipLaunchKernelGGL(attn_mlp_kernel, dim3(N_ATOMS / 8), dim3(1024), 0, stream,
                       q, kb, vb, pair, bidx, Wb, x, Wout, W1, b1, W2, b2, out);
}

// Round 5
// 43.568 us; speedup vs baseline: 2.2885x; 1.3556x over previous
//
#include <hip/hip_runtime.h>
#include <hip/hip_bf16.h>

#define N_ATOMS 2048
#define C_DIM   128
#define C_PAIR  16
#define BLK_K   128
#define LN_EPS  1e-5f

typedef float f32x4 __attribute__((ext_vector_type(4)));
typedef short s16x8 __attribute__((ext_vector_type(8)));

__device__ __forceinline__ float bf_lo(unsigned int p) {
    union { unsigned int i; float f; } u; u.i = p << 16; return u.f;
}
__device__ __forceinline__ float bf_hi(unsigned int p) {
    union { unsigned int i; float f; } u; u.i = p & 0xffff0000u; return u.f;
}
__device__ __forceinline__ float bf2f(unsigned short s) {
    union { unsigned int i; float f; } u; u.i = ((unsigned int)s) << 16; return u.f;
}
__device__ __forceinline__ unsigned short f2bf(float f) {
    union { float f; unsigned int i; } u; u.f = f;
    const unsigned int r = u.i + 0x7fffu + ((u.i >> 16) & 1u);  // RNE
    return (unsigned short)(r >> 16);
}

// A-fragment read from swizzled bf16 LDS tile [16][rowBytes/2].
// lane l: row m=l&15, k-bytes koff = kstep*64 + (l>>4)*16, XOR-swizzled.
__device__ __forceinline__ s16x8 lda_frag(const unsigned short* base,
                                          int rowBytes, int kstep, int lane) {
    const int m    = lane & 15;
    const int koff = kstep * 64 + ((lane >> 4) << 4);
    const int addr = m * rowBytes + (koff ^ ((m & 7) << 4));
    return *reinterpret_cast<const s16x8*>(
        reinterpret_cast<const char*>(base) + addr);
}

// ---------------------------------------------------------------------------
// Weight packing: W [Nout][K] f32 row-major -> bf16 B-fragment stream:
// unit = (ntile, kstep); lane l holds W[ntile*16+(l&15)][kstep*32+(l>>4)*8 +0..7]
// units: Wout 32 (8x4), W1 128 (32x4), W2 128 (8x16)  => 288 total
// ---------------------------------------------------------------------------
__device__ void pack_unit(int u, int lane,
                          const float* __restrict__ Wout,
                          const float* __restrict__ W1,
                          const float* __restrict__ W2,
                          unsigned short* __restrict__ WoutP,
                          unsigned short* __restrict__ W1P,
                          unsigned short* __restrict__ W2P)
{
    const float* W; unsigned short* P; int K, local;
    if (u < 32)       { W = Wout; P = WoutP; K = 128; local = u; }
    else if (u < 160) { W = W1;   P = W1P;   K = 128; local = u - 32; }
    else              { W = W2;   P = W2P;   K = 512; local = u - 160; }
    const int ksteps = K >> 5;
    const int ntile  = local / ksteps;
    const int kstep  = local - ntile * ksteps;
    const int n  = ntile * 16 + (lane & 15);
    const int k0 = kstep * 32 + ((lane >> 4) << 3);
    const float4* src = reinterpret_cast<const float4*>(W + (size_t)n * K + k0);
    const float4 a = src[0], b = src[1];
    s16x8 o;
    o[0] = (short)f2bf(a.x); o[1] = (short)f2bf(a.y);
    o[2] = (short)f2bf(a.z); o[3] = (short)f2bf(a.w);
    o[4] = (short)f2bf(b.x); o[5] = (short)f2bf(b.y);
    o[6] = (short)f2bf(b.z); o[7] = (short)f2bf(b.w);
    reinterpret_cast<s16x8*>(P)[local * 64 + lane] = o;
}

// ---------------------------------------------------------------------------
// K1: LayerNorm(x) -> h, q = h@Wq.T (f32), k/v = h@W.T (bf16) + weight packing
// ---------------------------------------------------------------------------
__global__ __launch_bounds__(768) void ln_qkv_kernel(
    const float* __restrict__ x,
    const float* __restrict__ Wq, const float* __restrict__ Wk,
    const float* __restrict__ Wv,
    const float* __restrict__ Wout, const float* __restrict__ W1,
    const float* __restrict__ W2,
    float* __restrict__ q,
    unsigned short* __restrict__ kb, unsigned short* __restrict__ vb,
    unsigned short* __restrict__ WoutP, unsigned short* __restrict__ W1P,
    unsigned short* __restrict__ W2P)
{
    __shared__ __align__(16) float hs[8][128];            // 4 KB
    __shared__ __align__(16) float part[2][3][8][128];    // 24 KB
    const int t = threadIdx.x;
    const int bid = blockIdx.x;
    const int row0 = bid * 8;

    // --- weight packing (one-time, spread over blocks) ---
    if (t < 64) pack_unit(bid, t, Wout, W1, W2, WoutP, W1P, W2P);
    else if (bid < 32 && t >= 64 && t < 128)
        pack_unit(256 + bid, t - 64, Wout, W1, W2, WoutP, W1P, W2P);

    if (t < 256) {
        const int r = t >> 5, l = t & 31;
        const float4 xv = reinterpret_cast<const float4*>(
            x + (size_t)(row0 + r) * C_DIM)[l];
        float s  = xv.x + xv.y + xv.z + xv.w;
        float ss = xv.x*xv.x + xv.y*xv.y + xv.z*xv.z + xv.w*xv.w;
        #pragma unroll
        for (int m = 16; m >= 1; m >>= 1) {
            s  += __shfl_xor(s,  m);
            ss += __shfl_xor(ss, m);
        }
        const float mu  = s * (1.0f / 128.0f);
        const float var = ss * (1.0f / 128.0f) - mu * mu;
        const float inv = rsqrtf(var + LN_EPS);
        float4 hv;
        hv.x = (xv.x - mu) * inv;
        hv.y = (xv.y - mu) * inv;
        hv.z = (xv.z - mu) * inv;
        hv.w = (xv.w - mu) * inv;
        *reinterpret_cast<float4*>(&hs[r][l * 4]) = hv;
    }
    __syncthreads();

    {
        const int p  = t >> 8;        // 0..2 projection
        const int u  = t & 255;
        const int c  = u & 127;       // output col
        const int kh = u >> 7;        // 0..1 K-half (64 each)
        const float* Wp = (p == 0) ? Wq : (p == 1) ? Wk : Wv;
        const float4* W4 = reinterpret_cast<const float4*>(
            Wp + (size_t)c * C_DIM + kh * 64);
        float acc[8] = {0.f,0.f,0.f,0.f,0.f,0.f,0.f,0.f};
        #pragma unroll
        for (int jq = 0; jq < 16; ++jq) {
            const float4 w4 = W4[jq];
            #pragma unroll
            for (int r = 0; r < 8; ++r) {
                const float4 h4 = *reinterpret_cast<const float4*>(
                    &hs[r][kh * 64 + jq * 4]);
                acc[r] += w4.x*h4.x + w4.y*h4.y + w4.z*h4.z + w4.w*h4.w;
            }
        }
        #pragma unroll
        for (int r = 0; r < 8; ++r) part[kh][p][r][c] = acc[r];
    }
    __syncthreads();

    {
        const int p  = t >> 8;
        const int u  = t & 255;
        const int c  = u & 127;
        const int rh = u >> 7;
        #pragma unroll
        for (int rr = 0; rr < 4; ++rr) {
            const int r = rh * 4 + rr;
            const float val = part[0][p][r][c] + part[1][p][r][c];
            const size_t off = (size_t)(row0 + r) * C_DIM + c;
            if (p == 0)      q[off]  = val;
            else if (p == 1) kb[off] = f2bf(val);
            else             vb[off] = f2bf(val);
        }
    }
}

// ---------------------------------------------------------------------------
// K2: fused attention (VALU) + proj/LN/MLP (bf16 MFMA). 1024 threads,
// 8 query rows per block, grid 256.
// ---------------------------------------------------------------------------
__global__ __launch_bounds__(1024) void attn_mlp_kernel(
    const float* __restrict__ q, const unsigned short* __restrict__ kb,
    const unsigned short* __restrict__ vb, const float* __restrict__ pair,
    const int*  __restrict__ bidx, const float* __restrict__ Wb,
    const float* __restrict__ x,
    const unsigned short* __restrict__ WoutP,
    const unsigned short* __restrict__ W1P, const float* __restrict__ b1,
    const unsigned short* __restrict__ W2P, const float* __restrict__ b2,
    float* __restrict__ out)
{
    __shared__ __align__(16) float qS[8][128];            // 4 KB
    __shared__ __align__(16) int   idxS[8][128];          // 4 KB
    __shared__ __align__(16) float S[8][4][128];          // 16 KB
    __shared__ __align__(16) float ys[8][128];            // 4 KB  x1 rows
    __shared__ __align__(16) unsigned short aoB[16][128]; // 4 KB  bf16 swz
    __shared__ __align__(16) unsigned short h2B[16][128]; // 4 KB  bf16 swz
    __shared__ __align__(16) unsigned short gsB[16][512]; // 16 KB bf16 swz

    const int t = threadIdx.x;
    const int row0 = blockIdx.x * 8;
    const int r = t >> 7;          // local row 0..7
    const int u = t & 127;         // key slot / dim
    const int row = row0 + r;
    const int wv = t >> 6, lane = t & 63;

    // --- A: stage q, idx, x; zero MFMA pad rows; issue pair gather ---
    const int j = bidx[(size_t)row * BLK_K + u];
    idxS[r][u] = j;
    qS[r][u] = q[(size_t)row * C_DIM + u];
    if (t < 256) {
        const int r2 = t >> 5, l = t & 31;
        const float4 xv = reinterpret_cast<const float4*>(
            x + (size_t)(row0 + r2) * C_DIM)[l];
        *reinterpret_cast<float4*>(&ys[r2][l * 4]) = xv;
    } else if (t < 384) {   // aoB rows 8..15 (2 KB)
        const uint4 z = {0,0,0,0};
        reinterpret_cast<uint4*>(&aoB[8][0])[t - 256] = z;
    } else if (t < 512) {   // h2B rows 8..15 (2 KB)
        const uint4 z = {0,0,0,0};
        reinterpret_cast<uint4*>(&h2B[8][0])[t - 384] = z;
    } else {                // gsB rows 8..15 (8 KB, 512 x 16B)
        const uint4 z = {0,0,0,0};
        reinterpret_cast<uint4*>(&gsB[8][0])[t - 512] = z;
    }
    const f32x4* pr = reinterpret_cast<const f32x4*>(
        pair + ((size_t)row * N_ATOMS + (size_t)j) * C_PAIR);
    const f32x4 p0 = __builtin_nontemporal_load(pr + 0);
    const f32x4 p1 = __builtin_nontemporal_load(pr + 1);
    const f32x4 p2 = __builtin_nontemporal_load(pr + 2);
    const f32x4 p3 = __builtin_nontemporal_load(pr + 3);
    __syncthreads();

    // --- scores: thread (r, u) dots q row r with bf16 k[j] for 4 heads ---
    {
        const uint4* kr = reinterpret_cast<const uint4*>(kb + (size_t)j * C_DIM);
        const float4* q4 = reinterpret_cast<const float4*>(&qS[r][0]);
        float sc[4];
        #pragma unroll
        for (int h = 0; h < 4; ++h) {
            float a = 0.f;
            #pragma unroll
            for (int d = 0; d < 4; ++d) {
                const uint4  kk = kr[h * 4 + d];
                const float4 qa = q4[h * 8 + d * 2];
                const float4 qc = q4[h * 8 + d * 2 + 1];
                a += bf_lo(kk.x)*qa.x + bf_hi(kk.x)*qa.y
                   + bf_lo(kk.y)*qa.z + bf_hi(kk.y)*qa.w;
                a += bf_lo(kk.z)*qc.x + bf_hi(kk.z)*qc.y
                   + bf_lo(kk.w)*qc.z + bf_hi(kk.w)*qc.w;
            }
            sc[h] = a;
        }
        const float pm = (p0.x+p0.y+p0.z+p0.w + p1.x+p1.y+p1.z+p1.w +
                          p2.x+p2.y+p2.z+p2.w + p3.x+p3.y+p3.z+p3.w) * (1.0f/16.0f);
        const float scale = 0.17677669529663687f;  // 1/sqrt(32)
        #pragma unroll
        for (int h = 0; h < 4; ++h)
            S[r][h][u] = sc[h] * scale + pm * Wb[h];
    }
    __syncthreads();

    // --- softmax per (row, head) ---
    {
        const int g = u >> 5, l = u & 31;
        const float v0 = S[r][g][l],      v1 = S[r][g][l + 32],
                    v2 = S[r][g][l + 64], v3 = S[r][g][l + 96];
        float mx = fmaxf(fmaxf(v0, v1), fmaxf(v2, v3));
        #pragma unroll
        for (int m = 16; m >= 1; m >>= 1) mx = fmaxf(mx, __shfl_xor(mx, m));
        const float e0 = __expf(v0 - mx), e1 = __expf(v1 - mx),
                    e2 = __expf(v2 - mx), e3 = __expf(v3 - mx);
        float sm = e0 + e1 + e2 + e3;
        #pragma unroll
        for (int m = 16; m >= 1; m >>= 1) sm += __shfl_xor(sm, m);
        const float rs = 1.0f / sm;
        S[r][g][l]      = e0 * rs;
        S[r][g][l + 32] = e1 * rs;
        S[r][g][l + 64] = e2 * rs;
        S[r][g][l + 96] = e3 * rs;
    }
    __syncthreads();

    // --- PV: thread (r, dim u); writes ao as swizzled bf16 (MFMA A tile) ---
    {
        const int hh = u >> 5;
        const float4* Sv = reinterpret_cast<const float4*>(&S[r][hh][0]);
        const int4*   iv = reinterpret_cast<const int4*>(&idxS[r][0]);
        float acc = 0.f;
        #pragma unroll 8
        for (int bq = 0; bq < 32; ++bq) {
            const float4 s4 = Sv[bq];
            const int4   j4 = iv[bq];
            acc += s4.x * bf2f(vb[(size_t)j4.x * C_DIM + u]);
            acc += s4.y * bf2f(vb[(size_t)j4.y * C_DIM + u]);
            acc += s4.z * bf2f(vb[(size_t)j4.z * C_DIM + u]);
            acc += s4.w * bf2f(vb[(size_t)j4.w * C_DIM + u]);
        }
        *reinterpret_cast<unsigned short*>(
            reinterpret_cast<char*>(&aoB[0][0]) +
            r * 256 + (((u * 2)) ^ ((r & 7) << 4))) = f2bf(acc);
    }
    __syncthreads();

    // --- P: x1 = x + ao @ Wout.T  (waves 0..7, wave w -> col tile w) ---
    if (wv < 8) {
        f32x4 acc = {0.f, 0.f, 0.f, 0.f};
        const s16x8* Bp = reinterpret_cast<const s16x8*>(WoutP);
        #pragma unroll
        for (int ks = 0; ks < 4; ++ks) {
            const s16x8 a = lda_frag(&aoB[0][0], 256, ks, lane);
            const s16x8 b = Bp[(wv * 4 + ks) * 64 + lane];
            acc = __builtin_amdgcn_mfma_f32_16x16x32_bf16(a, b, acc, 0, 0, 0);
        }
        if (lane < 32) {
            const int c = wv * 16 + (lane & 15);
            #pragma unroll
            for (int i = 0; i < 4; ++i) {
                const int m = ((lane >> 4) << 2) + i;   // 0..7
                ys[m][c] += acc[i];
            }
        }
    }
    __syncthreads();

    // --- LN: h2 = LayerNorm(x1) -> swizzled bf16 ---
    if (t < 256) {
        const int rr = t >> 5, l = t & 31;
        const float4 yv = *reinterpret_cast<const float4*>(&ys[rr][l * 4]);
        float s  = yv.x + yv.y + yv.z + yv.w;
        float ss = yv.x*yv.x + yv.y*yv.y + yv.z*yv.z + yv.w*yv.w;
        #pragma unroll
        for (int m = 16; m >= 1; m >>= 1) {
            s  += __shfl_xor(s,  m);
            ss += __shfl_xor(ss, m);
        }
        const float mu  = s * (1.0f / 128.0f);
        const float var = ss * (1.0f / 128.0f) - mu * mu;
        const float inv = rsqrtf(var + LN_EPS);
        union { unsigned long long u64; unsigned short u16[4]; } pk;
        pk.u16[0] = f2bf((yv.x - mu) * inv);
        pk.u16[1] = f2bf((yv.y - mu) * inv);
        pk.u16[2] = f2bf((yv.z - mu) * inv);
        pk.u16[3] = f2bf((yv.w - mu) * inv);
        *reinterpret_cast<unsigned long long*>(
            reinterpret_cast<char*>(&h2B[0][0]) +
            rr * 256 + ((l * 8) ^ ((rr & 7) << 4))) = pk.u64;
    }
    __syncthreads();

    // --- M1: gs = silu(h2 @ W1.T + b1)  (16 waves x 2 col tiles) ---
    {
        s16x8 afr[4];
        #pragma unroll
        for (int ks = 0; ks < 4; ++ks) afr[ks] = lda_frag(&h2B[0][0], 256, ks, lane);
        const s16x8* Bp = reinterpret_cast<const s16x8*>(W1P);
        #pragma unroll
        for (int tt = 0; tt < 2; ++tt) {
            const int tile = wv * 2 + tt;
            f32x4 acc = {0.f, 0.f, 0.f, 0.f};
            #pragma unroll
            for (int ks = 0; ks < 4; ++ks) {
                const s16x8 b = Bp[(tile * 4 + ks) * 64 + lane];
                acc = __builtin_amdgcn_mfma_f32_16x16x32_bf16(afr[ks], b, acc, 0, 0, 0);
            }
            if (lane < 32) {
                const int c = tile * 16 + (lane & 15);
                const float bb = b1[c];
                #pragma unroll
                for (int i = 0; i < 4; ++i) {
                    const int m = ((lane >> 4) << 2) + i;  // 0..7
                    const float g = acc[i] + bb;
                    const float sv = g / (1.0f + __expf(-g));
                    *reinterpret_cast<unsigned short*>(
                        reinterpret_cast<char*>(&gsB[0][0]) +
                        m * 1024 + ((c * 2) ^ ((m & 7) << 4))) = f2bf(sv);
                }
            }
        }
    }
    __syncthreads();

    // --- M2: out = x1 + gs @ W2.T + b2  (waves 0..7, K=512) ---
    if (wv < 8) {
        f32x4 acc = {0.f, 0.f, 0.f, 0.f};
        const s16x8* Bp = reinterpret_cast<const s16x8*>(W2P);
        #pragma unroll
        for (int ks = 0; ks < 16; ++ks) {
            const s16x8 a = lda_frag(&gsB[0][0], 1024, ks, lane);
            const s16x8 b = Bp[(wv * 16 + ks) * 64 + lane];
            acc = __builtin_amdgcn_mfma_f32_16x16x32_bf16(a, b, acc, 0, 0, 0);
        }
        if (lane < 32) {
            const int c = wv * 16 + (lane & 15);
            const float bb = b2[c];
            #pragma unroll
            for (int i = 0; i < 4; ++i) {
                const int m = ((lane >> 4) << 2) + i;   // 0..7
                out[(size_t)(row0 + m) * C_DIM + c] = ys[m][c] + bb + acc[i];
            }
        }
    }
}

// ---------------------------------------------------------------------------
extern "C" void kernel_launch(void* const* d_in, const int* in_sizes, int n_in,
                              void* d_out, int out_size, void* d_ws, size_t ws_size,
                              hipStream_t stream)
{
    const float* x    = (const float*)d_in[0];
    const float* pair = (const float*)d_in[1];
    const int*   bidx = (const int*)  d_in[2];
    const float* Wq   = (const float*)d_in[3];
    const float* Wk   = (const float*)d_in[4];
    const float* Wv   = (const float*)d_in[5];
    const float* Wb   = (const float*)d_in[6];
    const float* Wout = (const float*)d_in[7];
    const float* W1   = (const float*)d_in[8];
    const float* b1   = (const float*)d_in[9];
    const float* W2   = (const float*)d_in[10];
    const float* b2   = (const float*)d_in[11];
    float* out = (float*)d_out;

    char* ws = (char*)d_ws;
    float*          q     = (float*)ws;                               // 1 MB
    unsigned short* kb    = (unsigned short*)(ws + (1 << 20));        // 0.5 MB
    unsigned short* vb    = (unsigned short*)(ws + (1 << 20) + (1 << 19));
    unsigned short* WoutP = (unsigned short*)(ws + (2 << 20));        // 32 KB
    unsigned short* W1P   = (unsigned short*)(ws + (2 << 20) + (32 << 10));  // 128 KB
    unsigned short* W2P   = (unsigned short*)(ws + (2 << 20) + (160 << 10)); // 128 KB

    hipLaunchKernelGGL(ln_qkv_kernel, dim3(N_ATOMS / 8), dim3(768), 0, stream,
                       x, Wq, Wk, Wv, Wout, W1, W2, q, kb, vb, WoutP, W1P, W2P);
    hipLaunchKernelGGL(attn_mlp_kernel, dim3(N_ATOMS / 8), dim3(1024), 0, stream,
                       q, kb, vb, pair, bidx, Wb, x, WoutP, W1P, b1, W2P, b2, out);
}

// Round 6
// 42.755 us; speedup vs baseline: 2.3320x; 1.0190x over previous
//
#include <hip/hip_runtime.h>
#include <hip/hip_bf16.h>

#define N_ATOMS 2048
#define C_DIM   128
#define C_PAIR  16
#define BLK_K   128
#define LN_EPS  1e-5f

typedef float f32x4 __attribute__((ext_vector_type(4)));
typedef short s16x8 __attribute__((ext_vector_type(8)));

__device__ __forceinline__ float bf_lo(unsigned int p) {
    union { unsigned int i; float f; } u; u.i = p << 16; return u.f;
}
__device__ __forceinline__ float bf_hi(unsigned int p) {
    union { unsigned int i; float f; } u; u.i = p & 0xffff0000u; return u.f;
}
__device__ __forceinline__ float bf2f(unsigned short s) {
    union { unsigned int i; float f; } u; u.i = ((unsigned int)s) << 16; return u.f;
}
__device__ __forceinline__ unsigned short f2bf(float f) {
    union { float f; unsigned int i; } u; u.f = f;
    const unsigned int r = u.i + 0x7fffu + ((u.i >> 16) & 1u);  // RNE
    return (unsigned short)(r >> 16);
}

// A-fragment read from swizzled bf16 LDS tile [16][rowBytes/2].
// lane l: row m=l&15, k-bytes koff = kstep*64 + (l>>4)*16, XOR-swizzled.
__device__ __forceinline__ s16x8 lda_frag(const unsigned short* base,
                                          int rowBytes, int kstep, int lane) {
    const int m    = lane & 15;
    const int koff = kstep * 64 + ((lane >> 4) << 4);
    const int addr = m * rowBytes + (koff ^ ((m & 7) << 4));
    return *reinterpret_cast<const s16x8*>(
        reinterpret_cast<const char*>(base) + addr);
}

// ---------------------------------------------------------------------------
// Weight packing: W [Nout][K] f32 row-major -> bf16 B-fragment stream:
// unit = (ntile, kstep); lane l holds W[ntile*16+(l&15)][kstep*32+(l>>4)*8 +0..7]
// units: Wout 32 (8x4), W1 128 (32x4), W2 128 (8x16)  => 288 total
// ---------------------------------------------------------------------------
__device__ void pack_unit(int u, int lane,
                          const float* __restrict__ Wout,
                          const float* __restrict__ W1,
                          const float* __restrict__ W2,
                          unsigned short* __restrict__ WoutP,
                          unsigned short* __restrict__ W1P,
                          unsigned short* __restrict__ W2P)
{
    const float* W; unsigned short* P; int K, local;
    if (u < 32)       { W = Wout; P = WoutP; K = 128; local = u; }
    else if (u < 160) { W = W1;   P = W1P;   K = 128; local = u - 32; }
    else              { W = W2;   P = W2P;   K = 512; local = u - 160; }
    const int ksteps = K >> 5;
    const int ntile  = local / ksteps;
    const int kstep  = local - ntile * ksteps;
    const int n  = ntile * 16 + (lane & 15);
    const int k0 = kstep * 32 + ((lane >> 4) << 3);
    const float4* src = reinterpret_cast<const float4*>(W + (size_t)n * K + k0);
    const float4 a = src[0], b = src[1];
    s16x8 o;
    o[0] = (short)f2bf(a.x); o[1] = (short)f2bf(a.y);
    o[2] = (short)f2bf(a.z); o[3] = (short)f2bf(a.w);
    o[4] = (short)f2bf(b.x); o[5] = (short)f2bf(b.y);
    o[6] = (short)f2bf(b.z); o[7] = (short)f2bf(b.w);
    reinterpret_cast<s16x8*>(P)[local * 64 + lane] = o;
}

// ---------------------------------------------------------------------------
// K1: LayerNorm(x) -> swizzled bf16 LDS; q/k/v via MFMA with weight
// B-fragments loaded directly from f32 global (fragment layout, coalesced).
// 512 threads (8 waves), 16 rows per block, grid 128. Plus weight packing.
// ---------------------------------------------------------------------------
__global__ __launch_bounds__(512) void ln_qkv_kernel(
    const float* __restrict__ x,
    const float* __restrict__ Wq, const float* __restrict__ Wk,
    const float* __restrict__ Wv,
    const float* __restrict__ Wout, const float* __restrict__ W1,
    const float* __restrict__ W2,
    float* __restrict__ q,
    unsigned short* __restrict__ kb, unsigned short* __restrict__ vb,
    unsigned short* __restrict__ WoutP, unsigned short* __restrict__ W1P,
    unsigned short* __restrict__ W2P)
{
    __shared__ __align__(16) unsigned short hB[16][128];  // 4 KB swizzled bf16
    const int t = threadIdx.x;
    const int bid = blockIdx.x;
    const int row0 = bid * 16;

    // --- one-time weight packing for K2 (288 units over 128 blocks) ---
    if (t < 64)       pack_unit(bid * 2,     t,       Wout, W1, W2, WoutP, W1P, W2P);
    else if (t < 128) pack_unit(bid * 2 + 1, t - 64,  Wout, W1, W2, WoutP, W1P, W2P);
    else if (t < 192 && bid < 32)
                      pack_unit(256 + bid,   t - 128, Wout, W1, W2, WoutP, W1P, W2P);

    // --- LN: 32 lanes per row, 16 rows -> swizzled bf16 hB ---
    {
        const int r = t >> 5, l = t & 31;
        const float4 xv = reinterpret_cast<const float4*>(
            x + (size_t)(row0 + r) * C_DIM)[l];
        float s  = xv.x + xv.y + xv.z + xv.w;
        float ss = xv.x*xv.x + xv.y*xv.y + xv.z*xv.z + xv.w*xv.w;
        #pragma unroll
        for (int m = 16; m >= 1; m >>= 1) {
            s  += __shfl_xor(s,  m);
            ss += __shfl_xor(ss, m);
        }
        const float mu  = s * (1.0f / 128.0f);
        const float var = ss * (1.0f / 128.0f) - mu * mu;
        const float inv = rsqrtf(var + LN_EPS);
        union { unsigned long long u64; unsigned short u16[4]; } pk;
        pk.u16[0] = f2bf((xv.x - mu) * inv);
        pk.u16[1] = f2bf((xv.y - mu) * inv);
        pk.u16[2] = f2bf((xv.z - mu) * inv);
        pk.u16[3] = f2bf((xv.w - mu) * inv);
        *reinterpret_cast<unsigned long long*>(
            reinterpret_cast<char*>(&hB[0][0]) +
            r * 256 + ((l * 8) ^ ((r & 7) << 4))) = pk.u64;
    }
    __syncthreads();

    // --- q/k/v = h @ W.T via MFMA (wave wv -> col tile wv; 3 projections) ---
    {
        const int wv = t >> 6, lane = t & 63;
        s16x8 afr[4];
        #pragma unroll
        for (int ks = 0; ks < 4; ++ks) afr[ks] = lda_frag(&hB[0][0], 256, ks, lane);

        const int n = wv * 16 + (lane & 15);      // weight row = output col
        #pragma unroll
        for (int p = 0; p < 3; ++p) {
            const float* W = (p == 0) ? Wq : (p == 1) ? Wk : Wv;
            f32x4 acc = {0.f, 0.f, 0.f, 0.f};
            #pragma unroll
            for (int ks = 0; ks < 4; ++ks) {
                const int k0 = ks * 32 + ((lane >> 4) << 3);
                const float4* src = reinterpret_cast<const float4*>(
                    W + (size_t)n * C_DIM + k0);
                const float4 a = src[0], b = src[1];
                s16x8 bfr;
                bfr[0] = (short)f2bf(a.x); bfr[1] = (short)f2bf(a.y);
                bfr[2] = (short)f2bf(a.z); bfr[3] = (short)f2bf(a.w);
                bfr[4] = (short)f2bf(b.x); bfr[5] = (short)f2bf(b.y);
                bfr[6] = (short)f2bf(b.z); bfr[7] = (short)f2bf(b.w);
                acc = __builtin_amdgcn_mfma_f32_16x16x32_bf16(afr[ks], bfr, acc, 0, 0, 0);
            }
            #pragma unroll
            for (int ii = 0; ii < 4; ++ii) {
                const int m = ((lane >> 4) << 2) + ii;   // 0..15
                const size_t off = (size_t)(row0 + m) * C_DIM + n;
                if (p == 0)      q[off]  = acc[ii];
                else if (p == 1) kb[off] = f2bf(acc[ii]);
                else             vb[off] = f2bf(acc[ii]);
            }
        }
    }
}

// ---------------------------------------------------------------------------
// K2: fused attention (VALU) + proj/LN/MLP (bf16 MFMA). 1024 threads,
// 8 query rows per block, grid 256.  (unchanged from R4)
// ---------------------------------------------------------------------------
__global__ __launch_bounds__(1024) void attn_mlp_kernel(
    const float* __restrict__ q, const unsigned short* __restrict__ kb,
    const unsigned short* __restrict__ vb, const float* __restrict__ pair,
    const int*  __restrict__ bidx, const float* __restrict__ Wb,
    const float* __restrict__ x,
    const unsigned short* __restrict__ WoutP,
    const unsigned short* __restrict__ W1P, const float* __restrict__ b1,
    const unsigned short* __restrict__ W2P, const float* __restrict__ b2,
    float* __restrict__ out)
{
    __shared__ __align__(16) float qS[8][128];            // 4 KB
    __shared__ __align__(16) int   idxS[8][128];          // 4 KB
    __shared__ __align__(16) float S[8][4][128];          // 16 KB
    __shared__ __align__(16) float ys[8][128];            // 4 KB  x1 rows
    __shared__ __align__(16) unsigned short aoB[16][128]; // 4 KB  bf16 swz
    __shared__ __align__(16) unsigned short h2B[16][128]; // 4 KB  bf16 swz
    __shared__ __align__(16) unsigned short gsB[16][512]; // 16 KB bf16 swz

    const int t = threadIdx.x;
    const int row0 = blockIdx.x * 8;
    const int r = t >> 7;          // local row 0..7
    const int u = t & 127;         // key slot / dim
    const int row = row0 + r;
    const int wv = t >> 6, lane = t & 63;

    // --- A: stage q, idx, x; zero MFMA pad rows; issue pair gather ---
    const int j = bidx[(size_t)row * BLK_K + u];
    idxS[r][u] = j;
    qS[r][u] = q[(size_t)row * C_DIM + u];
    if (t < 256) {
        const int r2 = t >> 5, l = t & 31;
        const float4 xv = reinterpret_cast<const float4*>(
            x + (size_t)(row0 + r2) * C_DIM)[l];
        *reinterpret_cast<float4*>(&ys[r2][l * 4]) = xv;
    } else if (t < 384) {   // aoB rows 8..15 (2 KB)
        const uint4 z = {0,0,0,0};
        reinterpret_cast<uint4*>(&aoB[8][0])[t - 256] = z;
    } else if (t < 512) {   // h2B rows 8..15 (2 KB)
        const uint4 z = {0,0,0,0};
        reinterpret_cast<uint4*>(&h2B[8][0])[t - 384] = z;
    } else {                // gsB rows 8..15 (8 KB, 512 x 16B)
        const uint4 z = {0,0,0,0};
        reinterpret_cast<uint4*>(&gsB[8][0])[t - 512] = z;
    }
    const f32x4* pr = reinterpret_cast<const f32x4*>(
        pair + ((size_t)row * N_ATOMS + (size_t)j) * C_PAIR);
    const f32x4 p0 = __builtin_nontemporal_load(pr + 0);
    const f32x4 p1 = __builtin_nontemporal_load(pr + 1);
    const f32x4 p2 = __builtin_nontemporal_load(pr + 2);
    const f32x4 p3 = __builtin_nontemporal_load(pr + 3);
    __syncthreads();

    // --- scores: thread (r, u) dots q row r with bf16 k[j] for 4 heads ---
    {
        const uint4* kr = reinterpret_cast<const uint4*>(kb + (size_t)j * C_DIM);
        const float4* q4 = reinterpret_cast<const float4*>(&qS[r][0]);
        float sc[4];
        #pragma unroll
        for (int h = 0; h < 4; ++h) {
            float a = 0.f;
            #pragma unroll
            for (int d = 0; d < 4; ++d) {
                const uint4  kk = kr[h * 4 + d];
                const float4 qa = q4[h * 8 + d * 2];
                const float4 qc = q4[h * 8 + d * 2 + 1];
                a += bf_lo(kk.x)*qa.x + bf_hi(kk.x)*qa.y
                   + bf_lo(kk.y)*qa.z + bf_hi(kk.y)*qa.w;
                a += bf_lo(kk.z)*qc.x + bf_hi(kk.z)*qc.y
                   + bf_lo(kk.w)*qc.z + bf_hi(kk.w)*qc.w;
            }
            sc[h] = a;
        }
        const float pm = (p0.x+p0.y+p0.z+p0.w + p1.x+p1.y+p1.z+p1.w +
                          p2.x+p2.y+p2.z+p2.w + p3.x+p3.y+p3.z+p3.w) * (1.0f/16.0f);
        const float scale = 0.17677669529663687f;  // 1/sqrt(32)
        #pragma unroll
        for (int h = 0; h < 4; ++h)
            S[r][h][u] = sc[h] * scale + pm * Wb[h];
    }
    __syncthreads();

    // --- softmax per (row, head) ---
    {
        const int g = u >> 5, l = u & 31;
        const float v0 = S[r][g][l],      v1 = S[r][g][l + 32],
                    v2 = S[r][g][l + 64], v3 = S[r][g][l + 96];
        float mx = fmaxf(fmaxf(v0, v1), fmaxf(v2, v3));
        #pragma unroll
        for (int m = 16; m >= 1; m >>= 1) mx = fmaxf(mx, __shfl_xor(mx, m));
        const float e0 = __expf(v0 - mx), e1 = __expf(v1 - mx),
                    e2 = __expf(v2 - mx), e3 = __expf(v3 - mx);
        float sm = e0 + e1 + e2 + e3;
        #pragma unroll
        for (int m = 16; m >= 1; m >>= 1) sm += __shfl_xor(sm, m);
        const float rs = 1.0f / sm;
        S[r][g][l]      = e0 * rs;
        S[r][g][l + 32] = e1 * rs;
        S[r][g][l + 64] = e2 * rs;
        S[r][g][l + 96] = e3 * rs;
    }
    __syncthreads();

    // --- PV: thread (r, dim u); writes ao as swizzled bf16 (MFMA A tile) ---
    {
        const int hh = u >> 5;
        const float4* Sv = reinterpret_cast<const float4*>(&S[r][hh][0]);
        const int4*   iv = reinterpret_cast<const int4*>(&idxS[r][0]);
        float acc = 0.f;
        #pragma unroll 8
        for (int bq = 0; bq < 32; ++bq) {
            const float4 s4 = Sv[bq];
            const int4   j4 = iv[bq];
            acc += s4.x * bf2f(vb[(size_t)j4.x * C_DIM + u]);
            acc += s4.y * bf2f(vb[(size_t)j4.y * C_DIM + u]);
            acc += s4.z * bf2f(vb[(size_t)j4.z * C_DIM + u]);
            acc += s4.w * bf2f(vb[(size_t)j4.w * C_DIM + u]);
        }
        *reinterpret_cast<unsigned short*>(
            reinterpret_cast<char*>(&aoB[0][0]) +
            r * 256 + (((u * 2)) ^ ((r & 7) << 4))) = f2bf(acc);
    }
    __syncthreads();

    // --- P: x1 = x + ao @ Wout.T  (waves 0..7, wave w -> col tile w) ---
    if (wv < 8) {
        f32x4 acc = {0.f, 0.f, 0.f, 0.f};
        const s16x8* Bp = reinterpret_cast<const s16x8*>(WoutP);
        #pragma unroll
        for (int ks = 0; ks < 4; ++ks) {
            const s16x8 a = lda_frag(&aoB[0][0], 256, ks, lane);
            const s16x8 b = Bp[(wv * 4 + ks) * 64 + lane];
            acc = __builtin_amdgcn_mfma_f32_16x16x32_bf16(a, b, acc, 0, 0, 0);
        }
        if (lane < 32) {
            const int c = wv * 16 + (lane & 15);
            #pragma unroll
            for (int i = 0; i < 4; ++i) {
                const int m = ((lane >> 4) << 2) + i;   // 0..7
                ys[m][c] += acc[i];
            }
        }
    }
    __syncthreads();

    // --- LN: h2 = LayerNorm(x1) -> swizzled bf16 ---
    if (t < 256) {
        const int rr = t >> 5, l = t & 31;
        const float4 yv = *reinterpret_cast<const float4*>(&ys[rr][l * 4]);
        float s  = yv.x + yv.y + yv.z + yv.w;
        float ss = yv.x*yv.x + yv.y*yv.y + yv.z*yv.z + yv.w*yv.w;
        #pragma unroll
        for (int m = 16; m >= 1; m >>= 1) {
            s  += __shfl_xor(s,  m);
            ss += __shfl_xor(ss, m);
        }
        const float mu  = s * (1.0f / 128.0f);
        const float var = ss * (1.0f / 128.0f) - mu * mu;
        const float inv = rsqrtf(var + LN_EPS);
        union { unsigned long long u64; unsigned short u16[4]; } pk;
        pk.u16[0] = f2bf((yv.x - mu) * inv);
        pk.u16[1] = f2bf((yv.y - mu) * inv);
        pk.u16[2] = f2bf((yv.z - mu) * inv);
        pk.u16[3] = f2bf((yv.w - mu) * inv);
        *reinterpret_cast<unsigned long long*>(
            reinterpret_cast<char*>(&h2B[0][0]) +
            rr * 256 + ((l * 8) ^ ((rr & 7) << 4))) = pk.u64;
    }
    __syncthreads();

    // --- M1: gs = silu(h2 @ W1.T + b1)  (16 waves x 2 col tiles) ---
    {
        s16x8 afr[4];
        #pragma unroll
        for (int ks = 0; ks < 4; ++ks) afr[ks] = lda_frag(&h2B[0][0], 256, ks, lane);
        const s16x8* Bp = reinterpret_cast<const s16x8*>(W1P);
        #pragma unroll
        for (int tt = 0; tt < 2; ++tt) {
            const int tile = wv * 2 + tt;
            f32x4 acc = {0.f, 0.f, 0.f, 0.f};
            #pragma unroll
            for (int ks = 0; ks < 4; ++ks) {
                const s16x8 b = Bp[(tile * 4 + ks) * 64 + lane];
                acc = __builtin_amdgcn_mfma_f32_16x16x32_bf16(afr[ks], b, acc, 0, 0, 0);
            }
            if (lane < 32) {
                const int c = tile * 16 + (lane & 15);
                const float bb = b1[c];
                #pragma unroll
                for (int i = 0; i < 4; ++i) {
                    const int m = ((lane >> 4) << 2) + i;  // 0..7
                    const float g = acc[i] + bb;
                    const float sv = g / (1.0f + __expf(-g));
                    *reinterpret_cast<unsigned short*>(
                        reinterpret_cast<char*>(&gsB[0][0]) +
                        m * 1024 + ((c * 2) ^ ((m & 7) << 4))) = f2bf(sv);
                }
            }
        }
    }
    __syncthreads();

    // --- M2: out = x1 + gs @ W2.T + b2  (waves 0..7, K=512) ---
    if (wv < 8) {
        f32x4 acc = {0.f, 0.f, 0.f, 0.f};
        const s16x8* Bp = reinterpret_cast<const s16x8*>(W2P);
        #pragma unroll
        for (int ks = 0; ks < 16; ++ks) {
            const s16x8 a = lda_frag(&gsB[0][0], 1024, ks, lane);
            const s16x8 b = Bp[(wv * 16 + ks) * 64 + lane];
            acc = __builtin_amdgcn_mfma_f32_16x16x32_bf16(a, b, acc, 0, 0, 0);
        }
        if (lane < 32) {
            const int c = wv * 16 + (lane & 15);
            const float bb = b2[c];
            #pragma unroll
            for (int i = 0; i < 4; ++i) {
                const int m = ((lane >> 4) << 2) + i;   // 0..7
                out[(size_t)(row0 + m) * C_DIM + c] = ys[m][c] + bb + acc[i];
            }
        }
    }
}

// ---------------------------------------------------------------------------
extern "C" void kernel_launch(void* const* d_in, const int* in_sizes, int n_in,
                              void* d_out, int out_size, void* d_ws, size_t ws_size,
                              hipStream_t stream)
{
    const float* x    = (const float*)d_in[0];
    const float* pair = (const float*)d_in[1];
    const int*   bidx = (const int*)  d_in[2];
    const float* Wq   = (const float*)d_in[3];
    const float* Wk   = (const float*)d_in[4];
    const float* Wv   = (const float*)d_in[5];
    const float* Wb   = (const float*)d_in[6];
    const float* Wout = (const float*)d_in[7];
    const float* W1   = (const float*)d_in[8];
    const float* b1   = (const float*)d_in[9];
    const float* W2   = (const float*)d_in[10];
    const float* b2   = (const float*)d_in[11];
    float* out = (float*)d_out;

    char* ws = (char*)d_ws;
    float*          q     = (float*)ws;                               // 1 MB
    unsigned short* kb    = (unsigned short*)(ws + (1 << 20));        // 0.5 MB
    unsigned short* vb    = (unsigned short*)(ws + (1 << 20) + (1 << 19));
    unsigned short* WoutP = (unsigned short*)(ws + (2 << 20));        // 32 KB
    unsigned short* W1P   = (unsigned short*)(ws + (2 << 20) + (32 << 10));  // 128 KB
    unsigned short* W2P   = (unsigned short*)(ws + (2 << 20) + (160 << 10)); // 128 KB

    hipLaunchKernelGGL(ln_qkv_kernel, dim3(N_ATOMS / 16), dim3(512), 0, stream,
                       x, Wq, Wk, Wv, Wout, W1, W2, q, kb, vb, WoutP, W1P, W2P);
    hipLaunchKernelGGL(attn_mlp_kernel, dim3(N_ATOMS / 8), dim3(1024), 0, stream,
                       q, kb, vb, pair, bidx, Wb, x, WoutP, W1P, b1, W2P, b2, out);
}